// Round 9
// baseline (288.233 us; speedup 1.0000x reference)
//
#include <hip/hip_runtime.h>

#define NN 100000
#define NE 1600000
#define NM 10000
#define NSB 256
#define SUBN 391          // nodes per sub-bucket; 256*391 = 100096 >= NN
#define CAP2 7424         // per-sub-bucket edge capacity
#define PCH 2048

typedef __attribute__((ext_vector_type(8))) short bf16x8;
typedef __attribute__((ext_vector_type(4))) float f32x4;

__device__ inline float4 ld4(const float* p) { return *(const float4*)p; }
__device__ inline float bf2f(unsigned short u) {
  union { unsigned int i; float f; } c; c.i = ((unsigned int)u) << 16; return c.f;
}
__device__ inline unsigned short f2bf(float f) {
  union { float f; unsigned int i; } c; c.f = f;
  unsigned int u = c.i + 0x7fffu + ((c.i >> 16) & 1u);
  return (unsigned short)(u >> 16);
}
// swizzled LDS helpers (16B-chunk XOR swizzle)
__device__ inline void stx(unsigned char* base, int rowBytes, int row, int col,
                           unsigned short val) {
  int bc = col * 2;
  int c = bc >> 4, cp = c ^ (row & 15);
  *(unsigned short*)&base[row * rowBytes + (cp << 4) + (bc & 15)] = val;
}
__device__ inline bf16x8 ldx8(const unsigned char* base, int rowBytes, int row, int kc) {
  return *(const bf16x8*)&base[row * rowBytes + ((kc ^ (row & 15)) << 4)];
}

// ---------- 256-way edge partition, coalesced appends ----------
__global__ __launch_bounds__(256) void part2_k(const int* __restrict__ src,
                                               const int* __restrict__ dst,
                                               unsigned* __restrict__ parts2,
                                               int* __restrict__ pcnt2) {
  __shared__ int cntw[4][NSB];
  __shared__ int basew[4][NSB];
  __shared__ int bstart[NSB + 1];
  __shared__ int gbase[NSB];
  __shared__ int wsum[4];
  __shared__ unsigned buf[PCH];
  __shared__ unsigned char bb[PCH];
  const int tid = threadIdx.x;
  const int wv = tid >> 6;
  const int e0 = blockIdx.x * PCH;

  for (int i = tid; i < 4 * NSB; i += 256) ((int*)cntw)[i] = 0;
  __syncthreads();

  unsigned pk[8];
  int b_[8], lp_[8];
#pragma unroll
  for (int j = 0; j < 8; ++j) {
    int e = e0 + j * 256 + tid;
    bool ok = e < NE;
    int s = ok ? src[e] : 0;
    int d = ok ? dst[e] : 0;
    int b = d / SUBN;
    int ld = d - b * SUBN;
    pk[j] = ((unsigned)ld << 17) | (unsigned)s;
    b_[j] = ok ? b : -1;
    if (ok) lp_[j] = atomicAdd(&cntw[wv][b], 1);
  }
  __syncthreads();
  int t0 = cntw[0][tid], t1 = cntw[1][tid], t2 = cntw[2][tid], t3 = cntw[3][tid];
  int tot = t0 + t1 + t2 + t3;
  int x = tot;
#pragma unroll
  for (int d = 1; d < 64; d <<= 1) {
    int y = __shfl_up(x, d, 64);
    if ((tid & 63) >= d) x += y;
  }
  if ((tid & 63) == 63) wsum[wv] = x;
  __syncthreads();
  int woff = 0;
#pragma unroll
  for (int w = 0; w < 4; ++w) woff += (w < wv) ? wsum[w] : 0;
  int excl = x + woff - tot;
  bstart[tid] = excl;
  basew[0][tid] = excl;
  basew[1][tid] = excl + t0;
  basew[2][tid] = excl + t0 + t1;
  basew[3][tid] = excl + t0 + t1 + t2;
  gbase[tid] = atomicAdd(&pcnt2[tid], tot);
  if (tid == NSB - 1) bstart[NSB] = excl + tot;
  __syncthreads();
#pragma unroll
  for (int j = 0; j < 8; ++j)
    if (b_[j] >= 0) {
      int pos = basew[wv][b_[j]] + lp_[j];
      buf[pos] = pk[j];
      bb[pos] = (unsigned char)b_[j];
    }
  __syncthreads();
  int total = bstart[NSB];
  for (int i = tid; i < total; i += 256) {
    int b = bb[i];
    int gi = gbase[b] + (i - bstart[b]);
    if (gi < CAP2) parts2[(size_t)b * CAP2 + gi] = buf[i];
  }
}

// ---------- per-sub-bucket degree histogram ----------
__global__ __launch_bounds__(1024) void deg2_k(const unsigned* __restrict__ parts2,
                                               const int* __restrict__ pcnt2,
                                               int* __restrict__ deg) {
  __shared__ int cnt[SUBN];
  int sb = blockIdx.x;
  int n = min(pcnt2[sb], CAP2);
  const unsigned* p = parts2 + (size_t)sb * CAP2;
  for (int i = threadIdx.x; i < SUBN; i += 1024) cnt[i] = 0;
  __syncthreads();
  for (int i = threadIdx.x; i < n; i += 1024) atomicAdd(&cnt[p[i] >> 17], 1);
  __syncthreads();
  int base = sb * SUBN;
  for (int i = threadIdx.x; i < SUBN; i += 1024)
    if (base + i < NN) deg[base + i] = cnt[i];
}

__global__ __launch_bounds__(1024) void scan1_k(const int* __restrict__ deg,
                                                int* __restrict__ excl,
                                                int* __restrict__ bsum, int n) {
  __shared__ int lds[1024];
  int tid = threadIdx.x;
  int gid = blockIdx.x * 1024 + tid;
  int v = (gid < n) ? deg[gid] : 0;
  lds[tid] = v;
  __syncthreads();
  for (int off = 1; off < 1024; off <<= 1) {
    int t = (tid >= off) ? lds[tid - off] : 0;
    __syncthreads();
    lds[tid] += t;
    __syncthreads();
  }
  if (gid < n) excl[gid] = lds[tid] - v;
  if (tid == 1023) bsum[blockIdx.x] = lds[1023];
}

__global__ void scan2_k(int* __restrict__ bsum, int nb) {
  __shared__ int lds[128];
  int tid = threadIdx.x;
  int v = (tid < nb) ? bsum[tid] : 0;
  lds[tid] = v;
  __syncthreads();
  for (int off = 1; off < 128; off <<= 1) {
    int t = (tid >= off) ? lds[tid - off] : 0;
    __syncthreads();
    lds[tid] += t;
    __syncthreads();
  }
  if (tid < nb) bsum[tid] = lds[tid] - v;
}

// finalize: offs -> END offsets per node; inv = 1/max(deg,1)
__global__ __launch_bounds__(256) void scan3_k(int* __restrict__ excl,
                                               const int* __restrict__ bsum,
                                               const int* __restrict__ deg,
                                               float* __restrict__ inv, int n) {
  int gid = blockIdx.x * 256 + threadIdx.x;
  if (gid < n) {
    excl[gid] += bsum[gid >> 10] + deg[gid];
    inv[gid] = 1.0f / fmaxf((float)deg[gid], 1.0f);
  }
}

// ---------- per-sub-bucket LDS counting sort -> coalesced csr segment ----------
__global__ __launch_bounds__(1024) void sort_emit_k(const unsigned* __restrict__ parts2,
                                                    const int* __restrict__ pcnt2,
                                                    const int* __restrict__ offs_end,
                                                    const int* __restrict__ degv,
                                                    int* __restrict__ csr) {
  __shared__ int cur[SUBN];
  __shared__ int sorted[CAP2];
  int sb = blockIdx.x;
  int n = min(pcnt2[sb], CAP2);
  const unsigned* p = parts2 + (size_t)sb * CAP2;
  int base = sb * SUBN;
  int segbase = offs_end[base] - degv[base];
  for (int i = threadIdx.x; i < SUBN; i += 1024) {
    int nd = base + i;
    cur[i] = (nd < NN) ? (offs_end[nd] - degv[nd]) : 0;
  }
  __syncthreads();
  for (int i = threadIdx.x; i < n; i += 1024) {
    unsigned v = p[i];
    int pos = atomicAdd(&cur[v >> 17], 1);
    sorted[pos - segbase] = (int)(v & 0x1FFFFu);
  }
  __syncthreads();
  for (int i = threadIdx.x; i < n; i += 1024) csr[segbase + i] = sorted[i];
}

// ---------- fp32 feat -> bf16 SLICED layout [slice][node][16] ----------
__global__ __launch_bounds__(256) void tobfs_k(const float* __restrict__ feat,
                                               unsigned short* __restrict__ featsl) {
  int t = blockIdx.x * 256 + threadIdx.x;    // NN*16 threads
  int v = t >> 4, part = t & 15;
  if (v >= NN) return;
  float4 u = ld4(feat + (size_t)v * 128 + part * 8);
  float4 w = ld4(feat + (size_t)v * 128 + part * 8 + 4);
  unsigned short tmp[8];
  tmp[0] = f2bf(u.x); tmp[1] = f2bf(u.y); tmp[2] = f2bf(u.z); tmp[3] = f2bf(u.w);
  tmp[4] = f2bf(w.x); tmp[5] = f2bf(w.y); tmp[6] = f2bf(w.z); tmp[7] = f2bf(w.w);
  size_t idx = (size_t)(part >> 1) * NN * 2 + (size_t)v * 2 + (part & 1);
  ((uint4*)featsl)[idx] = *(const uint4*)tmp;
}

// ---------- weights -> bf16 fragment layout Wf[(kc*128+col)*8 + k&7] ----------
__device__ inline void convfrag(const float* W, unsigned short* Wf, int g) {
  int k8 = (g >> 7) << 3, col = g & 127;
  unsigned short tmp[8];
#pragma unroll
  for (int i = 0; i < 8; ++i) tmp[i] = f2bf(W[(k8 + i) * 128 + col]);
  *(uint4*)&Wf[(size_t)g * 8] = *(const uint4*)tmp;
}
__global__ __launch_bounds__(256) void wconv_k(const float* W1, const float* W2,
                                               const float* Wm1, const float* Wm2,
                                               const float* Wm3,
                                               unsigned short* W1f, unsigned short* W2f,
                                               unsigned short* Wm1f, unsigned short* Wm2f,
                                               unsigned short* Wm3f) {
  int g = blockIdx.x * 256 + threadIdx.x;
  if (g < 2048) convfrag(W1, W1f, g);
  else if (g < 4096) convfrag(W2, W2f, g - 2048);
  else if (g < 8192) convfrag(Wm1, Wm1f, g - 4096);
  else if (g < 10240) convfrag(Wm2, Wm2f, g - 8192);
  else if (g < 12288) convfrag(Wm3, Wm3f, g - 10240);
}

// ---------- mark needed nodes + pack meta2 for masked nodes ----------
__global__ __launch_bounds__(256) void mark_k(const int* __restrict__ masked,
                                              const int* __restrict__ csr,
                                              const int* __restrict__ offs_end,
                                              const int* __restrict__ degv,
                                              const float* __restrict__ inv,
                                              unsigned char* __restrict__ needed,
                                              uint4* __restrict__ meta2) {
  int m = blockIdx.x * 8 + (threadIdx.x >> 5);
  if (m >= NM) return;
  int lane = threadIdx.x & 31;
  int v = masked[m];
  int cnt = degv[v];
  int start = offs_end[v] - cnt;
  for (int i = lane; i < cnt; i += 32) needed[csr[start + i]] = 1;
  if (lane == 0)
    meta2[m] = make_uint4((unsigned)start, (unsigned)cnt,
                          (unsigned)__float_as_int(inv[v]), (unsigned)v);
}

// ---------- pack meta1 {start, cnt|-1, inv_bits, 0} ----------
__global__ __launch_bounds__(256) void meta1_k(const int* __restrict__ offs_end,
                                               const int* __restrict__ degv,
                                               const float* __restrict__ inv,
                                               const unsigned char* __restrict__ needed,
                                               uint4* __restrict__ meta1) {
  int gid = blockIdx.x * 256 + threadIdx.x;
  if (gid < NN) {
    int c = degv[gid];
    int st = offs_end[gid] - c;
    meta1[gid] = make_uint4((unsigned)st,
                            needed[gid] ? (unsigned)c : 0xFFFFFFFFu,
                            (unsigned)__float_as_int(inv[gid]), 0u);
  }
}

// ---------- sliced gather: wave-per-node, 8 edges x 8 colpairs, XCD-affine slice ----------
__global__ __launch_bounds__(256) void gatherS_k(const unsigned* __restrict__ fsl,
                                                 const int* __restrict__ csr,
                                                 const uint4* __restrict__ meta,
                                                 unsigned* __restrict__ outS,
                                                 int nNodes) {
  const int s = blockIdx.x & 7;
  const int g = blockIdx.x >> 3;
  const int wv = threadIdx.x >> 6, lane = threadIdx.x & 63;
  const int e = lane >> 3, c = lane & 7;
  const unsigned* fs = fsl + (size_t)s * NN * 8;     // slice base (src table = NN rows)
  unsigned* os = outS + (size_t)s * nNodes * 8;
  for (int i = 0; i < 16; ++i) {
    int v = g * 64 + wv * 16 + i;
    if (v >= nNodes) break;
    uint4 mt = meta[v];
    int cnt = (int)mt.y;
    if (cnt < 0) continue;                            // not needed
    int start = (int)mt.x;
    float iv = __int_as_float((int)mt.z);
    float a0 = 0.f, a1 = 0.f;
    for (int it = 0; it < cnt; it += 16) {
      int j0 = it + e, j1 = it + 8 + e;
      bool ok0 = j0 < cnt, ok1 = j1 < cnt;
      int i0 = csr[start + (ok0 ? j0 : 0)];
      int i1 = csr[start + (ok1 ? j1 : 0)];
      unsigned x0 = fs[(size_t)i0 * 8 + c];
      unsigned x1 = fs[(size_t)i1 * 8 + c];
      float m0 = ok0 ? 1.f : 0.f, m1 = ok1 ? 1.f : 0.f;
      a0 = fmaf(m0, bf2f((unsigned short)x0), a0);
      a1 = fmaf(m0, bf2f((unsigned short)(x0 >> 16)), a1);
      a0 = fmaf(m1, bf2f((unsigned short)x1), a0);
      a1 = fmaf(m1, bf2f((unsigned short)(x1 >> 16)), a1);
    }
    a0 += __shfl_xor(a0, 8); a0 += __shfl_xor(a0, 16); a0 += __shfl_xor(a0, 32);
    a1 += __shfl_xor(a1, 8); a1 += __shfl_xor(a1, 16); a1 += __shfl_xor(a1, 32);
    if (e == 0) {
      unsigned r = (unsigned)f2bf(a0 * iv) | ((unsigned)f2bf(a1 * iv) << 16);
      os[(size_t)v * 8 + c] = r;
    }
  }
}

// ---------- layer-1 MFMA: h1s = relu(agg1s @ W1 + b1), sliced in & out ----------
__global__ __launch_bounds__(256) void mfma1_k(const unsigned short* __restrict__ aggS,
                                               const unsigned short* __restrict__ W1f,
                                               const float* __restrict__ b1,
                                               unsigned short* __restrict__ h1S) {
  const int tid = threadIdx.x;
  const int wave = tid >> 6, lane = tid & 63, l15 = lane & 15, l4 = lane >> 4;
  const int rbase = blockIdx.x * 64;
  int col0 = wave * 16 + l15, col1 = (wave + 4) * 16 + l15;
  float bias0 = b1[col0], bias1 = b1[col1];
  for (int rsub = 0; rsub < 4; ++rsub) {
    int arow = rbase + rsub * 16 + l15;
    int ar = min(arow, NN - 1);
    f32x4 acc0 = {0.f, 0.f, 0.f, 0.f};
    f32x4 acc1 = {0.f, 0.f, 0.f, 0.f};
#pragma unroll
    for (int kt = 0; kt < 4; ++kt) {
      int kc = kt * 4 + l4;
      bf16x8 a = *(const bf16x8*)&aggS[(size_t)(kc >> 1) * NN * 16 + (size_t)ar * 16 + (kc & 1) * 8];
      bf16x8 b0 = *(const bf16x8*)&W1f[((size_t)kc * 128 + col0) * 8];
      bf16x8 b1v = *(const bf16x8*)&W1f[((size_t)kc * 128 + col1) * 8];
      acc0 = __builtin_amdgcn_mfma_f32_16x16x32_bf16(a, b0, acc0, 0, 0, 0);
      acc1 = __builtin_amdgcn_mfma_f32_16x16x32_bf16(a, b1v, acc1, 0, 0, 0);
    }
#pragma unroll
    for (int r = 0; r < 4; ++r) {
      int orow = rbase + rsub * 16 + l4 * 4 + r;
      if (orow < NN) {
        h1S[(size_t)wave * NN * 16 + (size_t)orow * 16 + l15] = f2bf(fmaxf(acc0[r] + bias0, 0.f));
        h1S[(size_t)(wave + 4) * NN * 16 + (size_t)orow * 16 + l15] = f2bf(fmaxf(acc1[r] + bias1, 0.f));
      }
    }
  }
}

// ---------- fused head: [relu(agg2@W2+b2), feat] -> 3-layer MLP -> out ----------
__global__ __launch_bounds__(256) void mlp_fused_k(const unsigned short* __restrict__ agg2S,
                                                   const unsigned short* __restrict__ featsl,
                                                   const int* __restrict__ masked,
                                                   const unsigned short* __restrict__ W2f,
                                                   const float* __restrict__ b2,
                                                   const unsigned short* __restrict__ Wm1f,
                                                   const float* __restrict__ bm1,
                                                   const unsigned short* __restrict__ Wm2f,
                                                   const float* __restrict__ bm2,
                                                   const unsigned short* __restrict__ Wm3f,
                                                   float* __restrict__ out) {
  __shared__ unsigned char ldsX[64 * 512];
  __shared__ unsigned char ldsY[64 * 256];
  const int tid = threadIdx.x;
  const int rbase = blockIdx.x * 64;
  const int wave = tid >> 6, lane = tid & 63, l15 = lane & 15, l4 = lane >> 4;
  // phase 0a: feat half of xcat (cols 128..255) from sliced feat
  {
    int grp = tid >> 5, ln = tid & 31;
    uint2 vals[8];
#pragma unroll
    for (int k = 0; k < 8; ++k) {
      int m = rbase + grp * 8 + k;
      vals[k] = make_uint2(0u, 0u);
      if (m < NM) {
        int v = masked[m];
        vals[k] = ((const uint2*)featsl)[(size_t)(ln >> 2) * NN * 4 + (size_t)v * 4 + (ln & 3)];
      }
    }
#pragma unroll
    for (int k = 0; k < 8; ++k) {
      int row = grp * 8 + k;
      int c = 16 + (ln >> 1);
      *(uint2*)&ldsX[row * 512 + ((c ^ (row & 15)) << 4) + (ln & 1) * 8] = vals[k];
    }
  }
  // phase 0b: left half = relu(agg2 @ W2 + b2), A from sliced global
  {
    int col0 = wave * 16 + l15, col1 = (wave + 4) * 16 + l15;
    float bias0 = b2[col0], bias1 = b2[col1];
    for (int rsub = 0; rsub < 4; ++rsub) {
      int arow = rbase + rsub * 16 + l15;
      int ar = min(arow, NM - 1);
      f32x4 acc0 = {0.f, 0.f, 0.f, 0.f};
      f32x4 acc1 = {0.f, 0.f, 0.f, 0.f};
#pragma unroll
      for (int kt = 0; kt < 4; ++kt) {
        int kc = kt * 4 + l4;
        bf16x8 a = *(const bf16x8*)&agg2S[(size_t)(kc >> 1) * NM * 16 + (size_t)ar * 16 + (kc & 1) * 8];
        bf16x8 b0 = *(const bf16x8*)&W2f[((size_t)kc * 128 + col0) * 8];
        bf16x8 b1v = *(const bf16x8*)&W2f[((size_t)kc * 128 + col1) * 8];
        acc0 = __builtin_amdgcn_mfma_f32_16x16x32_bf16(a, b0, acc0, 0, 0, 0);
        acc1 = __builtin_amdgcn_mfma_f32_16x16x32_bf16(a, b1v, acc1, 0, 0, 0);
      }
#pragma unroll
      for (int r = 0; r < 4; ++r) {
        int row = rsub * 16 + l4 * 4 + r;
        stx(ldsX, 512, row, col0, f2bf(fmaxf(acc0[r] + bias0, 0.f)));
        stx(ldsX, 512, row, col1, f2bf(fmaxf(acc1[r] + bias1, 0.f)));
      }
    }
  }
  __syncthreads();
  // phase 1: y1 = relu(xcat @ Wm1 + bm1), K=256
  {
    int col0 = wave * 16 + l15, col1 = (wave + 4) * 16 + l15;
    float bias0 = bm1[col0], bias1 = bm1[col1];
    for (int rsub = 0; rsub < 4; ++rsub) {
      int row = rsub * 16 + l15;
      f32x4 acc0 = {0.f, 0.f, 0.f, 0.f};
      f32x4 acc1 = {0.f, 0.f, 0.f, 0.f};
#pragma unroll
      for (int kt = 0; kt < 8; ++kt) {
        int kc = kt * 4 + l4;
        bf16x8 a = ldx8(ldsX, 512, row, kc);
        bf16x8 b0 = *(const bf16x8*)&Wm1f[((size_t)kc * 128 + col0) * 8];
        bf16x8 b1v = *(const bf16x8*)&Wm1f[((size_t)kc * 128 + col1) * 8];
        acc0 = __builtin_amdgcn_mfma_f32_16x16x32_bf16(a, b0, acc0, 0, 0, 0);
        acc1 = __builtin_amdgcn_mfma_f32_16x16x32_bf16(a, b1v, acc1, 0, 0, 0);
      }
#pragma unroll
      for (int r = 0; r < 4; ++r) {
        int row2 = rsub * 16 + l4 * 4 + r;
        stx(ldsY, 256, row2, col0, f2bf(fmaxf(acc0[r] + bias0, 0.f)));
        stx(ldsY, 256, row2, col1, f2bf(fmaxf(acc1[r] + bias1, 0.f)));
      }
    }
  }
  __syncthreads();
  // phase 2: y2 = relu(y1 @ Wm2 + bm2) -> ldsX (256B rows)
  {
    int col0 = wave * 16 + l15, col1 = (wave + 4) * 16 + l15;
    float bias0 = bm2[col0], bias1 = bm2[col1];
    for (int rsub = 0; rsub < 4; ++rsub) {
      int row = rsub * 16 + l15;
      f32x4 acc0 = {0.f, 0.f, 0.f, 0.f};
      f32x4 acc1 = {0.f, 0.f, 0.f, 0.f};
#pragma unroll
      for (int kt = 0; kt < 4; ++kt) {
        int kc = kt * 4 + l4;
        bf16x8 a = ldx8(ldsY, 256, row, kc);
        bf16x8 b0 = *(const bf16x8*)&Wm2f[((size_t)kc * 128 + col0) * 8];
        bf16x8 b1v = *(const bf16x8*)&Wm2f[((size_t)kc * 128 + col1) * 8];
        acc0 = __builtin_amdgcn_mfma_f32_16x16x32_bf16(a, b0, acc0, 0, 0, 0);
        acc1 = __builtin_amdgcn_mfma_f32_16x16x32_bf16(a, b1v, acc1, 0, 0, 0);
      }
#pragma unroll
      for (int r = 0; r < 4; ++r) {
        int row2 = rsub * 16 + l4 * 4 + r;
        stx(ldsX, 256, row2, col0, f2bf(fmaxf(acc0[r] + bias0, 0.f)));
        stx(ldsX, 256, row2, col1, f2bf(fmaxf(acc1[r] + bias1, 0.f)));
      }
    }
  }
  __syncthreads();
  // phase 3: out = y2 @ Wm3, fp32 global
  {
    int col0 = wave * 16 + l15, col1 = (wave + 4) * 16 + l15;
    for (int rsub = 0; rsub < 4; ++rsub) {
      int row = rsub * 16 + l15;
      f32x4 acc0 = {0.f, 0.f, 0.f, 0.f};
      f32x4 acc1 = {0.f, 0.f, 0.f, 0.f};
#pragma unroll
      for (int kt = 0; kt < 4; ++kt) {
        int kc = kt * 4 + l4;
        bf16x8 a = ldx8(ldsX, 256, row, kc);
        bf16x8 b0 = *(const bf16x8*)&Wm3f[((size_t)kc * 128 + col0) * 8];
        bf16x8 b1v = *(const bf16x8*)&Wm3f[((size_t)kc * 128 + col1) * 8];
        acc0 = __builtin_amdgcn_mfma_f32_16x16x32_bf16(a, b0, acc0, 0, 0, 0);
        acc1 = __builtin_amdgcn_mfma_f32_16x16x32_bf16(a, b1v, acc1, 0, 0, 0);
      }
#pragma unroll
      for (int r = 0; r < 4; ++r) {
        int orow = rbase + rsub * 16 + l4 * 4 + r;
        if (orow < NM) {
          out[(size_t)orow * 128 + col0] = acc0[r];
          out[(size_t)orow * 128 + col1] = acc1[r];
        }
      }
    }
  }
}

extern "C" void kernel_launch(void* const* d_in, const int* in_sizes, int n_in,
                              void* d_out, int out_size, void* d_ws, size_t ws_size,
                              hipStream_t stream) {
  const float* feat = (const float*)d_in[0];
  const int* src = (const int*)d_in[1];
  const int* dst = (const int*)d_in[2];
  const int* masked = (const int*)d_in[3];
  const float* W1 = (const float*)d_in[4];
  const float* b1 = (const float*)d_in[5];
  const float* W2 = (const float*)d_in[6];
  const float* b2 = (const float*)d_in[7];
  const float* Wm1 = (const float*)d_in[8];
  const float* bm1 = (const float*)d_in[9];
  const float* Wm2 = (const float*)d_in[10];
  const float* bm2 = (const float*)d_in[11];
  const float* Wm3 = (const float*)d_in[12];
  float* out = (float*)d_out;

  // ---- workspace layout ----
  char* p = (char*)d_ws;
  int* deg = (int*)p;              p += (size_t)NN * 4;
  int* offs = (int*)p;             p += (size_t)NN * 4;
  int* bsum = (int*)p;             p += 128 * 4;
  int* pcnt2 = (int*)p;            p += NSB * 4;
  float* inv = (float*)p;          p += (size_t)NN * 4;
  int* csr = (int*)p;              p += (size_t)NE * 4;
  unsigned char* needed = (unsigned char*)p; p += (size_t)NN;
  p = (char*)(((size_t)p + 15) & ~(size_t)15);
  uint4* meta1 = (uint4*)p;        p += (size_t)NN * 16;
  uint4* meta2 = (uint4*)p;        p += (size_t)NM * 16;
  unsigned* parts2 = (unsigned*)p; p += (size_t)NSB * CAP2 * 4;
  unsigned short* featsl = (unsigned short*)p;  p += (size_t)NN * 128 * 2;
  unsigned short* agg1S = (unsigned short*)p;   p += (size_t)NN * 128 * 2;
  unsigned short* h1S = (unsigned short*)p;     p += (size_t)NN * 128 * 2;
  unsigned short* agg2S = (unsigned short*)p;   p += (size_t)NM * 128 * 2;
  unsigned short* W1f = (unsigned short*)p;     p += 16384 * 2;
  unsigned short* W2f = (unsigned short*)p;     p += 16384 * 2;
  unsigned short* Wm1f = (unsigned short*)p;    p += 32768 * 2;
  unsigned short* Wm2f = (unsigned short*)p;    p += 16384 * 2;
  unsigned short* Wm3f = (unsigned short*)p;    p += 16384 * 2;

  (void)hipMemsetAsync(pcnt2, 0, NSB * 4, stream);
  (void)hipMemsetAsync(needed, 0, NN, stream);

  // sparse build
  part2_k<<<(NE + PCH - 1) / PCH, 256, 0, stream>>>(src, dst, parts2, pcnt2);
  deg2_k<<<NSB, 1024, 0, stream>>>(parts2, pcnt2, deg);
  int nb = (NN + 1023) / 1024;
  scan1_k<<<nb, 1024, 0, stream>>>(deg, offs, bsum, NN);
  scan2_k<<<1, 128, 0, stream>>>(bsum, nb);
  scan3_k<<<(NN + 255) / 256, 256, 0, stream>>>(offs, bsum, deg, inv, NN);
  sort_emit_k<<<NSB, 1024, 0, stream>>>(parts2, pcnt2, offs, deg, csr);

  // conversions (independent)
  tobfs_k<<<(NN * 16 + 255) / 256, 256, 0, stream>>>(feat, featsl);
  wconv_k<<<48, 256, 0, stream>>>(W1, W2, Wm1, Wm2, Wm3, W1f, W2f, Wm1f, Wm2f, Wm3f);

  // needed marking + meta packing
  mark_k<<<(NM + 7) / 8, 256, 0, stream>>>(masked, csr, offs, deg, inv, needed, meta2);
  meta1_k<<<(NN + 255) / 256, 256, 0, stream>>>(offs, deg, inv, needed, meta1);

  // layer 1: sliced gather (XCD-affine) + MFMA
  gatherS_k<<<8 * 1563, 256, 0, stream>>>((const unsigned*)featsl, csr, meta1,
                                          (unsigned*)agg1S, NN);
  mfma1_k<<<1563, 256, 0, stream>>>(agg1S, W1f, b1, h1S);

  // layer 2 at masked nodes: sliced gather of h1
  gatherS_k<<<8 * 157, 256, 0, stream>>>((const unsigned*)h1S, csr, meta2,
                                         (unsigned*)agg2S, NM);

  // fused head
  mlp_fused_k<<<157, 256, 0, stream>>>(agg2S, featsl, masked,
                                       W2f, b2, Wm1f, bm1, Wm2f, bm2, Wm3f, out);
}

// Round 10
// 185.110 us; speedup vs baseline: 1.5571x; 1.5571x over previous
//
#include <hip/hip_runtime.h>

#define NN 100000
#define NE 1600000
#define NM 10000
#define NSB 256
#define SUBN 391          // nodes per sub-bucket; 256*391 = 100096 >= NN
#define CAP2 7424         // per-sub-bucket edge capacity
#define PCH 2048

typedef __attribute__((ext_vector_type(8))) short bf16x8;
typedef __attribute__((ext_vector_type(4))) float f32x4;

__device__ inline float4 ld4(const float* p) { return *(const float4*)p; }
__device__ inline float bf2f(unsigned short u) {
  union { unsigned int i; float f; } c; c.i = ((unsigned int)u) << 16; return c.f;
}
__device__ inline unsigned short f2bf(float f) {
  union { float f; unsigned int i; } c; c.f = f;
  unsigned int u = c.i + 0x7fffu + ((c.i >> 16) & 1u);
  return (unsigned short)(u >> 16);
}
// swizzled LDS helpers (16B-chunk XOR swizzle)
__device__ inline void stx(unsigned char* base, int rowBytes, int row, int col,
                           unsigned short val) {
  int bc = col * 2;
  int c = bc >> 4, cp = c ^ (row & 15);
  *(unsigned short*)&base[row * rowBytes + (cp << 4) + (bc & 15)] = val;
}
__device__ inline bf16x8 ldx8(const unsigned char* base, int rowBytes, int row, int kc) {
  return *(const bf16x8*)&base[row * rowBytes + ((kc ^ (row & 15)) << 4)];
}

// ---------- 256-way edge partition, coalesced appends ----------
__global__ __launch_bounds__(256) void part2_k(const int* __restrict__ src,
                                               const int* __restrict__ dst,
                                               unsigned* __restrict__ parts2,
                                               int* __restrict__ pcnt2) {
  __shared__ int cntw[4][NSB];
  __shared__ int basew[4][NSB];
  __shared__ int bstart[NSB + 1];
  __shared__ int gbase[NSB];
  __shared__ int wsum[4];
  __shared__ unsigned buf[PCH];
  __shared__ unsigned char bb[PCH];
  const int tid = threadIdx.x;
  const int wv = tid >> 6;
  const int e0 = blockIdx.x * PCH;

  for (int i = tid; i < 4 * NSB; i += 256) ((int*)cntw)[i] = 0;
  __syncthreads();

  unsigned pk[8];
  int b_[8], lp_[8];
#pragma unroll
  for (int j = 0; j < 8; ++j) {
    int e = e0 + j * 256 + tid;
    bool ok = e < NE;
    int s = ok ? src[e] : 0;
    int d = ok ? dst[e] : 0;
    int b = d / SUBN;
    int ld = d - b * SUBN;
    pk[j] = ((unsigned)ld << 17) | (unsigned)s;
    b_[j] = ok ? b : -1;
    if (ok) lp_[j] = atomicAdd(&cntw[wv][b], 1);
  }
  __syncthreads();
  int t0 = cntw[0][tid], t1 = cntw[1][tid], t2 = cntw[2][tid], t3 = cntw[3][tid];
  int tot = t0 + t1 + t2 + t3;
  int x = tot;
#pragma unroll
  for (int d = 1; d < 64; d <<= 1) {
    int y = __shfl_up(x, d, 64);
    if ((tid & 63) >= d) x += y;
  }
  if ((tid & 63) == 63) wsum[wv] = x;
  __syncthreads();
  int woff = 0;
#pragma unroll
  for (int w = 0; w < 4; ++w) woff += (w < wv) ? wsum[w] : 0;
  int excl = x + woff - tot;
  bstart[tid] = excl;
  basew[0][tid] = excl;
  basew[1][tid] = excl + t0;
  basew[2][tid] = excl + t0 + t1;
  basew[3][tid] = excl + t0 + t1 + t2;
  gbase[tid] = atomicAdd(&pcnt2[tid], tot);
  if (tid == NSB - 1) bstart[NSB] = excl + tot;
  __syncthreads();
#pragma unroll
  for (int j = 0; j < 8; ++j)
    if (b_[j] >= 0) {
      int pos = basew[wv][b_[j]] + lp_[j];
      buf[pos] = pk[j];
      bb[pos] = (unsigned char)b_[j];
    }
  __syncthreads();
  int total = bstart[NSB];
  for (int i = tid; i < total; i += 256) {
    int b = bb[i];
    int gi = gbase[b] + (i - bstart[b]);
    if (gi < CAP2) parts2[(size_t)b * CAP2 + gi] = buf[i];
  }
}

// ---------- per-sub-bucket degree histogram ----------
__global__ __launch_bounds__(1024) void deg2_k(const unsigned* __restrict__ parts2,
                                               const int* __restrict__ pcnt2,
                                               int* __restrict__ deg) {
  __shared__ int cnt[SUBN];
  int sb = blockIdx.x;
  int n = min(pcnt2[sb], CAP2);
  const unsigned* p = parts2 + (size_t)sb * CAP2;
  for (int i = threadIdx.x; i < SUBN; i += 1024) cnt[i] = 0;
  __syncthreads();
  for (int i = threadIdx.x; i < n; i += 1024) atomicAdd(&cnt[p[i] >> 17], 1);
  __syncthreads();
  int base = sb * SUBN;
  for (int i = threadIdx.x; i < SUBN; i += 1024)
    if (base + i < NN) deg[base + i] = cnt[i];
}

__global__ __launch_bounds__(1024) void scan1_k(const int* __restrict__ deg,
                                                int* __restrict__ excl,
                                                int* __restrict__ bsum, int n) {
  __shared__ int lds[1024];
  int tid = threadIdx.x;
  int gid = blockIdx.x * 1024 + tid;
  int v = (gid < n) ? deg[gid] : 0;
  lds[tid] = v;
  __syncthreads();
  for (int off = 1; off < 1024; off <<= 1) {
    int t = (tid >= off) ? lds[tid - off] : 0;
    __syncthreads();
    lds[tid] += t;
    __syncthreads();
  }
  if (gid < n) excl[gid] = lds[tid] - v;
  if (tid == 1023) bsum[blockIdx.x] = lds[1023];
}

__global__ void scan2_k(int* __restrict__ bsum, int nb) {
  __shared__ int lds[128];
  int tid = threadIdx.x;
  int v = (tid < nb) ? bsum[tid] : 0;
  lds[tid] = v;
  __syncthreads();
  for (int off = 1; off < 128; off <<= 1) {
    int t = (tid >= off) ? lds[tid - off] : 0;
    __syncthreads();
    lds[tid] += t;
    __syncthreads();
  }
  if (tid < nb) bsum[tid] = lds[tid] - v;
}

// finalize: offs -> END offsets per node; inv = 1/max(deg,1)
__global__ __launch_bounds__(256) void scan3_k(int* __restrict__ excl,
                                               const int* __restrict__ bsum,
                                               const int* __restrict__ deg,
                                               float* __restrict__ inv, int n) {
  int gid = blockIdx.x * 256 + threadIdx.x;
  if (gid < n) {
    excl[gid] += bsum[gid >> 10] + deg[gid];
    inv[gid] = 1.0f / fmaxf((float)deg[gid], 1.0f);
  }
}

// ---------- per-sub-bucket LDS counting sort -> coalesced csr segment ----------
__global__ __launch_bounds__(1024) void sort_emit_k(const unsigned* __restrict__ parts2,
                                                    const int* __restrict__ pcnt2,
                                                    const int* __restrict__ offs_end,
                                                    const int* __restrict__ degv,
                                                    int* __restrict__ csr) {
  __shared__ int cur[SUBN];
  __shared__ int sorted[CAP2];
  int sb = blockIdx.x;
  int n = min(pcnt2[sb], CAP2);
  const unsigned* p = parts2 + (size_t)sb * CAP2;
  int base = sb * SUBN;
  int segbase = offs_end[base] - degv[base];
  for (int i = threadIdx.x; i < SUBN; i += 1024) {
    int nd = base + i;
    cur[i] = (nd < NN) ? (offs_end[nd] - degv[nd]) : 0;
  }
  __syncthreads();
  for (int i = threadIdx.x; i < n; i += 1024) {
    unsigned v = p[i];
    int pos = atomicAdd(&cur[v >> 17], 1);
    sorted[pos - segbase] = (int)(v & 0x1FFFFu);
  }
  __syncthreads();
  for (int i = threadIdx.x; i < n; i += 1024) csr[segbase + i] = sorted[i];
}

// ---------- fp32 -> bf16 bulk convert, [node][128] layout ----------
__global__ __launch_bounds__(256) void tobf_k(const float* __restrict__ x,
                                              unsigned short* __restrict__ y, int n) {
  int idx = (blockIdx.x * 256 + threadIdx.x) * 4;
  if (idx < n) {
    float4 v = ld4(x + idx);
    unsigned int lo = (unsigned int)f2bf(v.x) | ((unsigned int)f2bf(v.y) << 16);
    unsigned int hi = (unsigned int)f2bf(v.z) | ((unsigned int)f2bf(v.w) << 16);
    *(uint2*)(y + idx) = make_uint2(lo, hi);
  }
}

// ---------- weights -> bf16 fragment layout Wf[(kc*128+col)*8 + k&7] ----------
__device__ inline void convfrag(const float* W, unsigned short* Wf, int g) {
  int k8 = (g >> 7) << 3, col = g & 127;
  unsigned short tmp[8];
#pragma unroll
  for (int i = 0; i < 8; ++i) tmp[i] = f2bf(W[(k8 + i) * 128 + col]);
  *(uint4*)&Wf[(size_t)g * 8] = *(const uint4*)tmp;
}
__global__ __launch_bounds__(256) void wconv_k(const float* W1, const float* W2,
                                               const float* Wm1, const float* Wm2,
                                               const float* Wm3,
                                               unsigned short* W1f, unsigned short* W2f,
                                               unsigned short* Wm1f, unsigned short* Wm2f,
                                               unsigned short* Wm3f) {
  int g = blockIdx.x * 256 + threadIdx.x;
  if (g < 2048) convfrag(W1, W1f, g);
  else if (g < 4096) convfrag(W2, W2f, g - 2048);
  else if (g < 8192) convfrag(Wm1, Wm1f, g - 4096);
  else if (g < 10240) convfrag(Wm2, Wm2f, g - 8192);
  else if (g < 12288) convfrag(Wm3, Wm3f, g - 10240);
}

// ---------- mark nodes whose h1 is consumed by layer 2 ----------
__global__ __launch_bounds__(256) void mark_k(const int* __restrict__ masked,
                                              const int* __restrict__ csr,
                                              const int* __restrict__ offs_end,
                                              const int* __restrict__ degv,
                                              unsigned char* __restrict__ needed) {
  int m = blockIdx.x * 8 + (threadIdx.x >> 5);
  if (m >= NM) return;
  int lane = threadIdx.x & 31;
  int v = masked[m];
  int cnt = degv[v];
  int start = offs_end[v] - cnt;
  for (int i = lane; i < cnt; i += 32) needed[csr[start + i]] = 1;
}

// ---------- gather layer 1: only needed nodes; zero-row pad (index NN) ----------
__global__ __launch_bounds__(256) void gather1_k(const unsigned short* __restrict__ featbf,
                                                 const int* __restrict__ csr,
                                                 const int* __restrict__ offs_end,
                                                 const int* __restrict__ degv,
                                                 const float* __restrict__ inv,
                                                 const unsigned char* __restrict__ needed,
                                                 unsigned short* __restrict__ agg1) {
  int v = blockIdx.x * 8 + (threadIdx.x >> 5);
  if (v >= NN) return;
  if (!needed[v]) return;   // h1 row never read downstream
  int lane = threadIdx.x & 31;
  int cnt = degv[v];
  int start = offs_end[v] - cnt;
  const uint2* fb = (const uint2*)featbf;
  float a0 = 0.f, a1 = 0.f, a2 = 0.f, a3 = 0.f;
  int nb8 = (cnt + 7) >> 3;
  for (int it = 0; it < nb8; ++it) {
    int b = start + (it << 3);
    int rem = cnt - (it << 3);
    int sidx[8];
#pragma unroll
    for (int j = 0; j < 8; ++j) {
      int s = csr[b + (j < rem ? j : 0)];
      sidx[j] = (j < rem) ? s : NN;        // NN = zeroed pad row
    }
    uint2 x[8];
#pragma unroll
    for (int j = 0; j < 8; ++j) x[j] = fb[(size_t)sidx[j] * 32 + lane];
#pragma unroll
    for (int j = 0; j < 8; ++j) {
      a0 += bf2f((unsigned short)(x[j].x));
      a1 += bf2f((unsigned short)(x[j].x >> 16));
      a2 += bf2f((unsigned short)(x[j].y));
      a3 += bf2f((unsigned short)(x[j].y >> 16));
    }
  }
  float iv = inv[v];
  unsigned int lo = (unsigned int)f2bf(a0 * iv) | ((unsigned int)f2bf(a1 * iv) << 16);
  unsigned int hi = (unsigned int)f2bf(a2 * iv) | ((unsigned int)f2bf(a3 * iv) << 16);
  ((uint2*)agg1)[(size_t)v * 32 + lane] = make_uint2(lo, hi);
}

// ---------- layer-1 MFMA: h1 = relu(agg1 @ W1 + b1), B preloaded in regs ----------
__global__ __launch_bounds__(256) void mfma1_k(const unsigned short* __restrict__ agg1,
                                               const unsigned short* __restrict__ W1f,
                                               const float* __restrict__ b1,
                                               unsigned short* __restrict__ h1bf) {
  const int tid = threadIdx.x;
  const int wave = tid >> 6, lane = tid & 63, l15 = lane & 15, l4 = lane >> 4;
  const int rbase = blockIdx.x * 64;
  int col0 = wave * 16 + l15, col1 = (wave + 4) * 16 + l15;
  bf16x8 Bfr0[4], Bfr1[4];
#pragma unroll
  for (int kt = 0; kt < 4; ++kt) {
    int kc = kt * 4 + l4;
    Bfr0[kt] = *(const bf16x8*)&W1f[((size_t)kc * 128 + col0) * 8];
    Bfr1[kt] = *(const bf16x8*)&W1f[((size_t)kc * 128 + col1) * 8];
  }
  float bias0 = b1[col0], bias1 = b1[col1];
  for (int rsub = 0; rsub < 4; ++rsub) {
    int arow = rbase + rsub * 16 + l15;
    const unsigned short* ap = agg1 + (size_t)min(arow, NN - 1) * 128;
    f32x4 acc0 = {0.f, 0.f, 0.f, 0.f};
    f32x4 acc1 = {0.f, 0.f, 0.f, 0.f};
#pragma unroll
    for (int kt = 0; kt < 4; ++kt) {
      int kc = kt * 4 + l4;
      bf16x8 a = *(const bf16x8*)(ap + kc * 8);
      acc0 = __builtin_amdgcn_mfma_f32_16x16x32_bf16(a, Bfr0[kt], acc0, 0, 0, 0);
      acc1 = __builtin_amdgcn_mfma_f32_16x16x32_bf16(a, Bfr1[kt], acc1, 0, 0, 0);
    }
#pragma unroll
    for (int r = 0; r < 4; ++r) {
      int orow = rbase + rsub * 16 + l4 * 4 + r;
      if (orow < NN) {
        h1bf[(size_t)orow * 128 + col0] = f2bf(fmaxf(acc0[r] + bias0, 0.f));
        h1bf[(size_t)orow * 128 + col1] = f2bf(fmaxf(acc1[r] + bias1, 0.f));
      }
    }
  }
}

// ---------- gather layer 2 at masked nodes (zero-row pad at h1 row NN) ----------
__global__ __launch_bounds__(256) void gather2_k(const unsigned short* __restrict__ h1bf,
                                                 const int* __restrict__ masked,
                                                 const int* __restrict__ csr,
                                                 const int* __restrict__ offs_end,
                                                 const int* __restrict__ degv,
                                                 const float* __restrict__ inv,
                                                 unsigned short* __restrict__ agg2bf) {
  int m = blockIdx.x * 8 + (threadIdx.x >> 5);
  if (m >= NM) return;
  int lane = threadIdx.x & 31;
  int v = masked[m];
  int cnt = degv[v];
  int start = offs_end[v] - cnt;
  const uint2* fb = (const uint2*)h1bf;
  float a0 = 0.f, a1 = 0.f, a2 = 0.f, a3 = 0.f;
  int nb8 = (cnt + 7) >> 3;
  for (int it = 0; it < nb8; ++it) {
    int b = start + (it << 3);
    int rem = cnt - (it << 3);
    int sidx[8];
#pragma unroll
    for (int j = 0; j < 8; ++j) {
      int s = csr[b + (j < rem ? j : 0)];
      sidx[j] = (j < rem) ? s : NN;
    }
    uint2 x[8];
#pragma unroll
    for (int j = 0; j < 8; ++j) x[j] = fb[(size_t)sidx[j] * 32 + lane];
#pragma unroll
    for (int j = 0; j < 8; ++j) {
      a0 += bf2f((unsigned short)(x[j].x));
      a1 += bf2f((unsigned short)(x[j].x >> 16));
      a2 += bf2f((unsigned short)(x[j].y));
      a3 += bf2f((unsigned short)(x[j].y >> 16));
    }
  }
  float iv = inv[v];
  unsigned int lo = (unsigned int)f2bf(a0 * iv) | ((unsigned int)f2bf(a1 * iv) << 16);
  unsigned int hi = (unsigned int)f2bf(a2 * iv) | ((unsigned int)f2bf(a3 * iv) << 16);
  ((uint2*)agg2bf)[(size_t)m * 32 + lane] = make_uint2(lo, hi);
}

// ---------- fused head: xcat build + 3-layer MLP, tiles LDS-resident ----------
__global__ __launch_bounds__(256) void mlp_fused_k(const unsigned short* __restrict__ agg2bf,
                                                   const unsigned short* __restrict__ featbf,
                                                   const int* __restrict__ masked,
                                                   const unsigned short* __restrict__ W2f,
                                                   const float* __restrict__ b2,
                                                   const unsigned short* __restrict__ Wm1f,
                                                   const float* __restrict__ bm1,
                                                   const unsigned short* __restrict__ Wm2f,
                                                   const float* __restrict__ bm2,
                                                   const unsigned short* __restrict__ Wm3f,
                                                   float* __restrict__ out) {
  __shared__ unsigned char ldsX[64 * 512];
  __shared__ unsigned char ldsY[64 * 256];
  const int tid = threadIdx.x;
  const int rbase = blockIdx.x * 64;
  const int wave = tid >> 6, lane = tid & 63, l15 = lane & 15, l4 = lane >> 4;
  // phase 0a: feat half of xcat (cols 128..255)
  {
    int grp = tid >> 5, ln = tid & 31;
    uint2 vals[8];
#pragma unroll
    for (int k = 0; k < 8; ++k) {
      int m = rbase + grp * 8 + k;
      vals[k] = make_uint2(0u, 0u);
      if (m < NM) {
        int v = masked[m];
        vals[k] = ((const uint2*)featbf)[(size_t)v * 32 + ln];
      }
    }
#pragma unroll
    for (int k = 0; k < 8; ++k) {
      int row = grp * 8 + k;
      int c = 16 + (ln >> 1);
      *(uint2*)&ldsX[row * 512 + ((c ^ (row & 15)) << 4) + (ln & 1) * 8] = vals[k];
    }
  }
  // phase 0b: left half = relu(agg2 @ W2 + b2)
  {
    int col0 = wave * 16 + l15, col1 = (wave + 4) * 16 + l15;
    float bias0 = b2[col0], bias1 = b2[col1];
    for (int rsub = 0; rsub < 4; ++rsub) {
      int arow = rbase + rsub * 16 + l15;
      const unsigned short* ap = agg2bf + (size_t)min(arow, NM - 1) * 128;
      f32x4 acc0 = {0.f, 0.f, 0.f, 0.f};
      f32x4 acc1 = {0.f, 0.f, 0.f, 0.f};
#pragma unroll
      for (int kt = 0; kt < 4; ++kt) {
        int kc = kt * 4 + l4;
        bf16x8 a = *(const bf16x8*)(ap + kc * 8);
        bf16x8 b0 = *(const bf16x8*)&W2f[((size_t)kc * 128 + col0) * 8];
        bf16x8 b1v = *(const bf16x8*)&W2f[((size_t)kc * 128 + col1) * 8];
        acc0 = __builtin_amdgcn_mfma_f32_16x16x32_bf16(a, b0, acc0, 0, 0, 0);
        acc1 = __builtin_amdgcn_mfma_f32_16x16x32_bf16(a, b1v, acc1, 0, 0, 0);
      }
#pragma unroll
      for (int r = 0; r < 4; ++r) {
        int row = rsub * 16 + l4 * 4 + r;
        stx(ldsX, 512, row, col0, f2bf(fmaxf(acc0[r] + bias0, 0.f)));
        stx(ldsX, 512, row, col1, f2bf(fmaxf(acc1[r] + bias1, 0.f)));
      }
    }
  }
  __syncthreads();
  // phase 1: y1 = relu(xcat @ Wm1 + bm1), K=256
  {
    int col0 = wave * 16 + l15, col1 = (wave + 4) * 16 + l15;
    float bias0 = bm1[col0], bias1 = bm1[col1];
    for (int rsub = 0; rsub < 4; ++rsub) {
      int row = rsub * 16 + l15;
      f32x4 acc0 = {0.f, 0.f, 0.f, 0.f};
      f32x4 acc1 = {0.f, 0.f, 0.f, 0.f};
#pragma unroll
      for (int kt = 0; kt < 8; ++kt) {
        int kc = kt * 4 + l4;
        bf16x8 a = ldx8(ldsX, 512, row, kc);
        bf16x8 b0 = *(const bf16x8*)&Wm1f[((size_t)kc * 128 + col0) * 8];
        bf16x8 b1v = *(const bf16x8*)&Wm1f[((size_t)kc * 128 + col1) * 8];
        acc0 = __builtin_amdgcn_mfma_f32_16x16x32_bf16(a, b0, acc0, 0, 0, 0);
        acc1 = __builtin_amdgcn_mfma_f32_16x16x32_bf16(a, b1v, acc1, 0, 0, 0);
      }
#pragma unroll
      for (int r = 0; r < 4; ++r) {
        int row2 = rsub * 16 + l4 * 4 + r;
        stx(ldsY, 256, row2, col0, f2bf(fmaxf(acc0[r] + bias0, 0.f)));
        stx(ldsY, 256, row2, col1, f2bf(fmaxf(acc1[r] + bias1, 0.f)));
      }
    }
  }
  __syncthreads();
  // phase 2: y2 = relu(y1 @ Wm2 + bm2) -> ldsX (256B rows)
  {
    int col0 = wave * 16 + l15, col1 = (wave + 4) * 16 + l15;
    float bias0 = bm2[col0], bias1 = bm2[col1];
    for (int rsub = 0; rsub < 4; ++rsub) {
      int row = rsub * 16 + l15;
      f32x4 acc0 = {0.f, 0.f, 0.f, 0.f};
      f32x4 acc1 = {0.f, 0.f, 0.f, 0.f};
#pragma unroll
      for (int kt = 0; kt < 4; ++kt) {
        int kc = kt * 4 + l4;
        bf16x8 a = ldx8(ldsY, 256, row, kc);
        bf16x8 b0 = *(const bf16x8*)&Wm2f[((size_t)kc * 128 + col0) * 8];
        bf16x8 b1v = *(const bf16x8*)&Wm2f[((size_t)kc * 128 + col1) * 8];
        acc0 = __builtin_amdgcn_mfma_f32_16x16x32_bf16(a, b0, acc0, 0, 0, 0);
        acc1 = __builtin_amdgcn_mfma_f32_16x16x32_bf16(a, b1v, acc1, 0, 0, 0);
      }
#pragma unroll
      for (int r = 0; r < 4; ++r) {
        int row2 = rsub * 16 + l4 * 4 + r;
        stx(ldsX, 256, row2, col0, f2bf(fmaxf(acc0[r] + bias0, 0.f)));
        stx(ldsX, 256, row2, col1, f2bf(fmaxf(acc1[r] + bias1, 0.f)));
      }
    }
  }
  __syncthreads();
  // phase 3: out = y2 @ Wm3, fp32 global
  {
    int col0 = wave * 16 + l15, col1 = (wave + 4) * 16 + l15;
    for (int rsub = 0; rsub < 4; ++rsub) {
      int row = rsub * 16 + l15;
      f32x4 acc0 = {0.f, 0.f, 0.f, 0.f};
      f32x4 acc1 = {0.f, 0.f, 0.f, 0.f};
#pragma unroll
      for (int kt = 0; kt < 4; ++kt) {
        int kc = kt * 4 + l4;
        bf16x8 a = ldx8(ldsX, 256, row, kc);
        bf16x8 b0 = *(const bf16x8*)&Wm3f[((size_t)kc * 128 + col0) * 8];
        bf16x8 b1v = *(const bf16x8*)&Wm3f[((size_t)kc * 128 + col1) * 8];
        acc0 = __builtin_amdgcn_mfma_f32_16x16x32_bf16(a, b0, acc0, 0, 0, 0);
        acc1 = __builtin_amdgcn_mfma_f32_16x16x32_bf16(a, b1v, acc1, 0, 0, 0);
      }
#pragma unroll
      for (int r = 0; r < 4; ++r) {
        int orow = rbase + rsub * 16 + l4 * 4 + r;
        if (orow < NM) {
          out[(size_t)orow * 128 + col0] = acc0[r];
          out[(size_t)orow * 128 + col1] = acc1[r];
        }
      }
    }
  }
}

extern "C" void kernel_launch(void* const* d_in, const int* in_sizes, int n_in,
                              void* d_out, int out_size, void* d_ws, size_t ws_size,
                              hipStream_t stream) {
  const float* feat = (const float*)d_in[0];
  const int* src = (const int*)d_in[1];
  const int* dst = (const int*)d_in[2];
  const int* masked = (const int*)d_in[3];
  const float* W1 = (const float*)d_in[4];
  const float* b1 = (const float*)d_in[5];
  const float* W2 = (const float*)d_in[6];
  const float* b2 = (const float*)d_in[7];
  const float* Wm1 = (const float*)d_in[8];
  const float* bm1 = (const float*)d_in[9];
  const float* Wm2 = (const float*)d_in[10];
  const float* bm2 = (const float*)d_in[11];
  const float* Wm3 = (const float*)d_in[12];
  float* out = (float*)d_out;

  // ---- workspace layout ----
  char* p = (char*)d_ws;
  int* deg = (int*)p;              p += (size_t)NN * 4;
  int* offs = (int*)p;             p += (size_t)NN * 4;
  int* bsum = (int*)p;             p += 128 * 4;
  int* pcnt2 = (int*)p;            p += NSB * 4;
  float* inv = (float*)p;          p += (size_t)NN * 4;
  int* csr = (int*)p;              p += (size_t)NE * 4;
  unsigned char* needed = (unsigned char*)p; p += (size_t)NN;
  p = (char*)(((size_t)p + 15) & ~(size_t)15);
  unsigned* parts2 = (unsigned*)p; p += (size_t)NSB * CAP2 * 4;
  unsigned short* featbf = (unsigned short*)p;  p += (size_t)(NN + 1) * 128 * 2;
  unsigned short* agg1 = (unsigned short*)p;    p += (size_t)NN * 128 * 2;
  unsigned short* h1bf = (unsigned short*)p;    p += (size_t)(NN + 1) * 128 * 2;
  unsigned short* agg2bf = (unsigned short*)p;  p += (size_t)NM * 128 * 2;
  unsigned short* W1f = (unsigned short*)p;     p += 16384 * 2;
  unsigned short* W2f = (unsigned short*)p;     p += 16384 * 2;
  unsigned short* Wm1f = (unsigned short*)p;    p += 32768 * 2;
  unsigned short* Wm2f = (unsigned short*)p;    p += 16384 * 2;
  unsigned short* Wm3f = (unsigned short*)p;    p += 16384 * 2;

  (void)hipMemsetAsync(pcnt2, 0, NSB * 4, stream);
  (void)hipMemsetAsync(needed, 0, NN, stream);
  (void)hipMemsetAsync(featbf + (size_t)NN * 128, 0, 256, stream);  // zero pad row
  (void)hipMemsetAsync(h1bf + (size_t)NN * 128, 0, 256, stream);    // zero pad row

  // sparse build: 256-way partition -> histogram -> scan -> LDS counting sort
  part2_k<<<(NE + PCH - 1) / PCH, 256, 0, stream>>>(src, dst, parts2, pcnt2);
  deg2_k<<<NSB, 1024, 0, stream>>>(parts2, pcnt2, deg);
  int nb = (NN + 1023) / 1024;
  scan1_k<<<nb, 1024, 0, stream>>>(deg, offs, bsum, NN);
  scan2_k<<<1, 128, 0, stream>>>(bsum, nb);
  scan3_k<<<(NN + 255) / 256, 256, 0, stream>>>(offs, bsum, deg, inv, NN);
  sort_emit_k<<<NSB, 1024, 0, stream>>>(parts2, pcnt2, offs, deg, csr);

  // conversions
  tobf_k<<<(NN * 128 / 4 + 255) / 256, 256, 0, stream>>>(feat, featbf, NN * 128);
  wconv_k<<<48, 256, 0, stream>>>(W1, W2, Wm1, Wm2, Wm3, W1f, W2f, Wm1f, Wm2f, Wm3f);

  // mark nodes needed by layer 2
  mark_k<<<(NM + 7) / 8, 256, 0, stream>>>(masked, csr, offs, deg, needed);

  // GCN layer 1: gather (needed only) + MFMA
  gather1_k<<<(NN + 7) / 8, 256, 0, stream>>>(featbf, csr, offs, deg, inv, needed, agg1);
  mfma1_k<<<(NN + 63) / 64, 256, 0, stream>>>(agg1, W1f, b1, h1bf);

  // layer-2 aggregation at masked nodes
  gather2_k<<<(NM + 7) / 8, 256, 0, stream>>>(h1bf, masked, csr, offs, deg, inv, agg2bf);

  // fused head
  mlp_fused_k<<<(NM + 63) / 64, 256, 0, stream>>>(agg2bf, featbf, masked,
                                                  W2f, b2, Wm1f, bm1, Wm2f, bm2, Wm3f, out);
}

// Round 11
// 158.597 us; speedup vs baseline: 1.8174x; 1.1672x over previous
//
#include <hip/hip_runtime.h>

#define NN 100000
#define NE 1600000
#define NM 10000
#define NSB 256
#define SUBN 391          // nodes per sub-bucket; 256*391 = 100096 >= NN
#define CAP2 7424         // per-sub-bucket edge capacity
#define PCH 2048
#define NBP2 782          // part2 blocks
#define NBTB 1600         // tobf blocks
#define NBWC 48           // wconv blocks

typedef __attribute__((ext_vector_type(8))) short bf16x8;
typedef __attribute__((ext_vector_type(4))) float f32x4;

__device__ inline float4 ld4(const float* p) { return *(const float4*)p; }
__device__ inline float bf2f(unsigned short u) {
  union { unsigned int i; float f; } c; c.i = ((unsigned int)u) << 16; return c.f;
}
__device__ inline unsigned short f2bf(float f) {
  union { float f; unsigned int i; } c; c.f = f;
  unsigned int u = c.i + 0x7fffu + ((c.i >> 16) & 1u);
  return (unsigned short)(u >> 16);
}
// swizzled LDS helpers (16B-chunk XOR swizzle)
__device__ inline void stx(unsigned char* base, int rowBytes, int row, int col,
                           unsigned short val) {
  int bc = col * 2;
  int c = bc >> 4, cp = c ^ (row & 15);
  *(unsigned short*)&base[row * rowBytes + (cp << 4) + (bc & 15)] = val;
}
__device__ inline bf16x8 ldx8(const unsigned char* base, int rowBytes, int row, int kc) {
  return *(const bf16x8*)&base[row * rowBytes + ((kc ^ (row & 15)) << 4)];
}

__device__ inline void convfrag(const float* W, unsigned short* Wf, int g) {
  int k8 = (g >> 7) << 3, col = g & 127;
  unsigned short tmp[8];
#pragma unroll
  for (int i = 0; i < 8; ++i) tmp[i] = f2bf(W[(k8 + i) * 128 + col]);
  *(uint4*)&Wf[(size_t)g * 8] = *(const uint4*)tmp;
}

// ---------- merged front: part2 partition ∥ feat->bf16 ∥ weight conv ∥ pad zero ----------
__global__ __launch_bounds__(256) void front_k(const int* __restrict__ src,
                                               const int* __restrict__ dst,
                                               unsigned* __restrict__ parts2,
                                               int* __restrict__ pcnt2,
                                               const float* __restrict__ feat,
                                               unsigned short* __restrict__ featbf,
                                               const float* W1, const float* W2,
                                               const float* Wm1, const float* Wm2,
                                               const float* Wm3,
                                               unsigned short* W1f, unsigned short* W2f,
                                               unsigned short* Wm1f, unsigned short* Wm2f,
                                               unsigned short* Wm3f,
                                               unsigned short* __restrict__ h1bf) {
  __shared__ int cntw[4][NSB];
  __shared__ int basew[4][NSB];
  __shared__ int bstart[NSB + 1];
  __shared__ int gbase[NSB];
  __shared__ int wsum[4];
  __shared__ unsigned buf[PCH];
  __shared__ unsigned char bb[PCH];
  const int bid = blockIdx.x;
  const int tid = threadIdx.x;

  if (bid < NBP2) {
    // ---- role: 256-way edge partition ----
    const int wv = tid >> 6;
    const int e0 = bid * PCH;
    for (int i = tid; i < 4 * NSB; i += 256) ((int*)cntw)[i] = 0;
    __syncthreads();
    unsigned pk[8];
    int b_[8], lp_[8];
#pragma unroll
    for (int j = 0; j < 8; ++j) {
      int e = e0 + j * 256 + tid;
      bool ok = e < NE;
      int s = ok ? src[e] : 0;
      int d = ok ? dst[e] : 0;
      int b = d / SUBN;
      int ld = d - b * SUBN;
      pk[j] = ((unsigned)ld << 17) | (unsigned)s;
      b_[j] = ok ? b : -1;
      if (ok) lp_[j] = atomicAdd(&cntw[wv][b], 1);
    }
    __syncthreads();
    int t0 = cntw[0][tid], t1 = cntw[1][tid], t2 = cntw[2][tid], t3 = cntw[3][tid];
    int tot = t0 + t1 + t2 + t3;
    int x = tot;
#pragma unroll
    for (int d = 1; d < 64; d <<= 1) {
      int y = __shfl_up(x, d, 64);
      if ((tid & 63) >= d) x += y;
    }
    if ((tid & 63) == 63) wsum[wv] = x;
    __syncthreads();
    int woff = 0;
#pragma unroll
    for (int w = 0; w < 4; ++w) woff += (w < wv) ? wsum[w] : 0;
    int excl = x + woff - tot;
    bstart[tid] = excl;
    basew[0][tid] = excl;
    basew[1][tid] = excl + t0;
    basew[2][tid] = excl + t0 + t1;
    basew[3][tid] = excl + t0 + t1 + t2;
    gbase[tid] = atomicAdd(&pcnt2[tid], tot);
    if (tid == NSB - 1) bstart[NSB] = excl + tot;
    __syncthreads();
#pragma unroll
    for (int j = 0; j < 8; ++j)
      if (b_[j] >= 0) {
        int pos = basew[wv][b_[j]] + lp_[j];
        buf[pos] = pk[j];
        bb[pos] = (unsigned char)b_[j];
      }
    __syncthreads();
    int total = bstart[NSB];
    for (int i = tid; i < total; i += 256) {
      int b = bb[i];
      int gi = gbase[b] + (i - bstart[b]);
      if (gi < CAP2) parts2[(size_t)b * CAP2 + gi] = buf[i];
    }
  } else if (bid < NBP2 + NBTB) {
    // ---- role: feat fp32 -> bf16 ----
    const int n4 = NN * 128 / 4;
    for (int i = (bid - NBP2) * 256 + tid; i < n4; i += NBTB * 256) {
      float4 v = ld4(feat + (size_t)i * 4);
      unsigned int lo = (unsigned int)f2bf(v.x) | ((unsigned int)f2bf(v.y) << 16);
      unsigned int hi = (unsigned int)f2bf(v.z) | ((unsigned int)f2bf(v.w) << 16);
      ((uint2*)featbf)[i] = make_uint2(lo, hi);
    }
  } else if (bid < NBP2 + NBTB + NBWC) {
    // ---- role: weights -> bf16 fragment layout ----
    int g = (bid - NBP2 - NBTB) * 256 + tid;
    if (g < 2048) convfrag(W1, W1f, g);
    else if (g < 4096) convfrag(W2, W2f, g - 2048);
    else if (g < 8192) convfrag(Wm1, Wm1f, g - 4096);
    else if (g < 10240) convfrag(Wm2, Wm2f, g - 8192);
    else if (g < 12288) convfrag(Wm3, Wm3f, g - 10240);
  } else {
    // ---- role: zero pad rows (featbf[NN], h1bf[NN]) ----
    if (tid < 64) {
      ((unsigned*)(featbf + (size_t)NN * 128))[tid] = 0u;
      ((unsigned*)(h1bf + (size_t)NN * 128))[tid] = 0u;
    }
  }
}

// ---------- per-sub-bucket degree histogram ----------
__global__ __launch_bounds__(1024) void deg2_k(const unsigned* __restrict__ parts2,
                                               const int* __restrict__ pcnt2,
                                               int* __restrict__ deg) {
  __shared__ int cnt[SUBN];
  int sb = blockIdx.x;
  int n = min(pcnt2[sb], CAP2);
  const unsigned* p = parts2 + (size_t)sb * CAP2;
  for (int i = threadIdx.x; i < SUBN; i += 1024) cnt[i] = 0;
  __syncthreads();
  for (int i = threadIdx.x; i < n; i += 1024) atomicAdd(&cnt[p[i] >> 17], 1);
  __syncthreads();
  int base = sb * SUBN;
  for (int i = threadIdx.x; i < SUBN; i += 1024)
    if (base + i < NN) deg[base + i] = cnt[i];
}

__global__ __launch_bounds__(1024) void scan1_k(const int* __restrict__ deg,
                                                int* __restrict__ excl,
                                                int* __restrict__ bsum, int n) {
  __shared__ int lds[1024];
  int tid = threadIdx.x;
  int gid = blockIdx.x * 1024 + tid;
  int v = (gid < n) ? deg[gid] : 0;
  lds[tid] = v;
  __syncthreads();
  for (int off = 1; off < 1024; off <<= 1) {
    int t = (tid >= off) ? lds[tid - off] : 0;
    __syncthreads();
    lds[tid] += t;
    __syncthreads();
  }
  if (gid < n) excl[gid] = lds[tid] - v;
  if (tid == 1023) bsum[blockIdx.x] = lds[1023];
}

__global__ void scan2_k(int* __restrict__ bsum, int nb) {
  __shared__ int lds[128];
  int tid = threadIdx.x;
  int v = (tid < nb) ? bsum[tid] : 0;
  lds[tid] = v;
  __syncthreads();
  for (int off = 1; off < 128; off <<= 1) {
    int t = (tid >= off) ? lds[tid - off] : 0;
    __syncthreads();
    lds[tid] += t;
    __syncthreads();
  }
  if (tid < nb) bsum[tid] = lds[tid] - v;
}

// finalize: offs -> END offsets per node; inv = 1/max(deg,1)
__global__ __launch_bounds__(256) void scan3_k(int* __restrict__ excl,
                                               const int* __restrict__ bsum,
                                               const int* __restrict__ deg,
                                               float* __restrict__ inv, int n) {
  int gid = blockIdx.x * 256 + threadIdx.x;
  if (gid < n) {
    excl[gid] += bsum[gid >> 10] + deg[gid];
    inv[gid] = 1.0f / fmaxf((float)deg[gid], 1.0f);
  }
}

// ---------- per-sub-bucket LDS counting sort -> coalesced csr segment ----------
__global__ __launch_bounds__(1024) void sort_emit_k(const unsigned* __restrict__ parts2,
                                                    const int* __restrict__ pcnt2,
                                                    const int* __restrict__ offs_end,
                                                    const int* __restrict__ degv,
                                                    int* __restrict__ csr) {
  __shared__ int cur[SUBN];
  __shared__ int sorted[CAP2];
  int sb = blockIdx.x;
  int n = min(pcnt2[sb], CAP2);
  const unsigned* p = parts2 + (size_t)sb * CAP2;
  int base = sb * SUBN;
  int segbase = offs_end[base] - degv[base];
  for (int i = threadIdx.x; i < SUBN; i += 1024) {
    int nd = base + i;
    cur[i] = (nd < NN) ? (offs_end[nd] - degv[nd]) : 0;
  }
  __syncthreads();
  for (int i = threadIdx.x; i < n; i += 1024) {
    unsigned v = p[i];
    int pos = atomicAdd(&cur[v >> 17], 1);
    sorted[pos - segbase] = (int)(v & 0x1FFFFu);
  }
  __syncthreads();
  for (int i = threadIdx.x; i < n; i += 1024) csr[segbase + i] = sorted[i];
}

// ---------- gather layer 1: all nodes; zero-row pad (index NN) for tail ----------
__global__ __launch_bounds__(256) void gather1_k(const unsigned short* __restrict__ featbf,
                                                 const int* __restrict__ csr,
                                                 const int* __restrict__ offs_end,
                                                 const int* __restrict__ degv,
                                                 const float* __restrict__ inv,
                                                 unsigned short* __restrict__ agg1) {
  int v = blockIdx.x * 8 + (threadIdx.x >> 5);
  if (v >= NN) return;
  int lane = threadIdx.x & 31;
  int cnt = degv[v];
  int start = offs_end[v] - cnt;
  const uint2* fb = (const uint2*)featbf;
  float a0 = 0.f, a1 = 0.f, a2 = 0.f, a3 = 0.f;
  int nb8 = (cnt + 7) >> 3;
  for (int it = 0; it < nb8; ++it) {
    int b = start + (it << 3);
    int rem = cnt - (it << 3);
    int sidx[8];
#pragma unroll
    for (int j = 0; j < 8; ++j) {
      int s = csr[b + (j < rem ? j : 0)];
      sidx[j] = (j < rem) ? s : NN;        // NN = zeroed pad row
    }
    uint2 x[8];
#pragma unroll
    for (int j = 0; j < 8; ++j) x[j] = fb[(size_t)sidx[j] * 32 + lane];
#pragma unroll
    for (int j = 0; j < 8; ++j) {
      a0 += bf2f((unsigned short)(x[j].x));
      a1 += bf2f((unsigned short)(x[j].x >> 16));
      a2 += bf2f((unsigned short)(x[j].y));
      a3 += bf2f((unsigned short)(x[j].y >> 16));
    }
  }
  float iv = inv[v];
  unsigned int lo = (unsigned int)f2bf(a0 * iv) | ((unsigned int)f2bf(a1 * iv) << 16);
  unsigned int hi = (unsigned int)f2bf(a2 * iv) | ((unsigned int)f2bf(a3 * iv) << 16);
  ((uint2*)agg1)[(size_t)v * 32 + lane] = make_uint2(lo, hi);
}

// ---------- layer-1 MFMA: h1 = relu(agg1 @ W1 + b1), B preloaded in regs ----------
__global__ __launch_bounds__(256) void mfma1_k(const unsigned short* __restrict__ agg1,
                                               const unsigned short* __restrict__ W1f,
                                               const float* __restrict__ b1,
                                               unsigned short* __restrict__ h1bf) {
  const int tid = threadIdx.x;
  const int wave = tid >> 6, lane = tid & 63, l15 = lane & 15, l4 = lane >> 4;
  const int rbase = blockIdx.x * 64;
  int col0 = wave * 16 + l15, col1 = (wave + 4) * 16 + l15;
  bf16x8 Bfr0[4], Bfr1[4];
#pragma unroll
  for (int kt = 0; kt < 4; ++kt) {
    int kc = kt * 4 + l4;
    Bfr0[kt] = *(const bf16x8*)&W1f[((size_t)kc * 128 + col0) * 8];
    Bfr1[kt] = *(const bf16x8*)&W1f[((size_t)kc * 128 + col1) * 8];
  }
  float bias0 = b1[col0], bias1 = b1[col1];
  for (int rsub = 0; rsub < 4; ++rsub) {
    int arow = rbase + rsub * 16 + l15;
    const unsigned short* ap = agg1 + (size_t)min(arow, NN - 1) * 128;
    f32x4 acc0 = {0.f, 0.f, 0.f, 0.f};
    f32x4 acc1 = {0.f, 0.f, 0.f, 0.f};
#pragma unroll
    for (int kt = 0; kt < 4; ++kt) {
      int kc = kt * 4 + l4;
      bf16x8 a = *(const bf16x8*)(ap + kc * 8);
      acc0 = __builtin_amdgcn_mfma_f32_16x16x32_bf16(a, Bfr0[kt], acc0, 0, 0, 0);
      acc1 = __builtin_amdgcn_mfma_f32_16x16x32_bf16(a, Bfr1[kt], acc1, 0, 0, 0);
    }
#pragma unroll
    for (int r = 0; r < 4; ++r) {
      int orow = rbase + rsub * 16 + l4 * 4 + r;
      if (orow < NN) {
        h1bf[(size_t)orow * 128 + col0] = f2bf(fmaxf(acc0[r] + bias0, 0.f));
        h1bf[(size_t)orow * 128 + col1] = f2bf(fmaxf(acc1[r] + bias1, 0.f));
      }
    }
  }
}

// ---------- gather layer 2 at masked nodes (zero-row pad at h1 row NN) ----------
__global__ __launch_bounds__(256) void gather2_k(const unsigned short* __restrict__ h1bf,
                                                 const int* __restrict__ masked,
                                                 const int* __restrict__ csr,
                                                 const int* __restrict__ offs_end,
                                                 const int* __restrict__ degv,
                                                 const float* __restrict__ inv,
                                                 unsigned short* __restrict__ agg2bf) {
  int m = blockIdx.x * 8 + (threadIdx.x >> 5);
  if (m >= NM) return;
  int lane = threadIdx.x & 31;
  int v = masked[m];
  int cnt = degv[v];
  int start = offs_end[v] - cnt;
  const uint2* fb = (const uint2*)h1bf;
  float a0 = 0.f, a1 = 0.f, a2 = 0.f, a3 = 0.f;
  int nb8 = (cnt + 7) >> 3;
  for (int it = 0; it < nb8; ++it) {
    int b = start + (it << 3);
    int rem = cnt - (it << 3);
    int sidx[8];
#pragma unroll
    for (int j = 0; j < 8; ++j) {
      int s = csr[b + (j < rem ? j : 0)];
      sidx[j] = (j < rem) ? s : NN;
    }
    uint2 x[8];
#pragma unroll
    for (int j = 0; j < 8; ++j) x[j] = fb[(size_t)sidx[j] * 32 + lane];
#pragma unroll
    for (int j = 0; j < 8; ++j) {
      a0 += bf2f((unsigned short)(x[j].x));
      a1 += bf2f((unsigned short)(x[j].x >> 16));
      a2 += bf2f((unsigned short)(x[j].y));
      a3 += bf2f((unsigned short)(x[j].y >> 16));
    }
  }
  float iv = inv[v];
  unsigned int lo = (unsigned int)f2bf(a0 * iv) | ((unsigned int)f2bf(a1 * iv) << 16);
  unsigned int hi = (unsigned int)f2bf(a2 * iv) | ((unsigned int)f2bf(a3 * iv) << 16);
  ((uint2*)agg2bf)[(size_t)m * 32 + lane] = make_uint2(lo, hi);
}

// ---------- fused head: xcat build + 3-layer MLP, tiles LDS-resident ----------
__global__ __launch_bounds__(256) void mlp_fused_k(const unsigned short* __restrict__ agg2bf,
                                                   const unsigned short* __restrict__ featbf,
                                                   const int* __restrict__ masked,
                                                   const unsigned short* __restrict__ W2f,
                                                   const float* __restrict__ b2,
                                                   const unsigned short* __restrict__ Wm1f,
                                                   const float* __restrict__ bm1,
                                                   const unsigned short* __restrict__ Wm2f,
                                                   const float* __restrict__ bm2,
                                                   const unsigned short* __restrict__ Wm3f,
                                                   float* __restrict__ out) {
  __shared__ unsigned char ldsX[64 * 512];
  __shared__ unsigned char ldsY[64 * 256];
  const int tid = threadIdx.x;
  const int rbase = blockIdx.x * 64;
  const int wave = tid >> 6, lane = tid & 63, l15 = lane & 15, l4 = lane >> 4;
  // phase 0a: feat half of xcat (cols 128..255)
  {
    int grp = tid >> 5, ln = tid & 31;
    uint2 vals[8];
#pragma unroll
    for (int k = 0; k < 8; ++k) {
      int m = rbase + grp * 8 + k;
      vals[k] = make_uint2(0u, 0u);
      if (m < NM) {
        int v = masked[m];
        vals[k] = ((const uint2*)featbf)[(size_t)v * 32 + ln];
      }
    }
#pragma unroll
    for (int k = 0; k < 8; ++k) {
      int row = grp * 8 + k;
      int c = 16 + (ln >> 1);
      *(uint2*)&ldsX[row * 512 + ((c ^ (row & 15)) << 4) + (ln & 1) * 8] = vals[k];
    }
  }
  // phase 0b: left half = relu(agg2 @ W2 + b2)
  {
    int col0 = wave * 16 + l15, col1 = (wave + 4) * 16 + l15;
    float bias0 = b2[col0], bias1 = b2[col1];
    for (int rsub = 0; rsub < 4; ++rsub) {
      int arow = rbase + rsub * 16 + l15;
      const unsigned short* ap = agg2bf + (size_t)min(arow, NM - 1) * 128;
      f32x4 acc0 = {0.f, 0.f, 0.f, 0.f};
      f32x4 acc1 = {0.f, 0.f, 0.f, 0.f};
#pragma unroll
      for (int kt = 0; kt < 4; ++kt) {
        int kc = kt * 4 + l4;
        bf16x8 a = *(const bf16x8*)(ap + kc * 8);
        bf16x8 b0 = *(const bf16x8*)&W2f[((size_t)kc * 128 + col0) * 8];
        bf16x8 b1v = *(const bf16x8*)&W2f[((size_t)kc * 128 + col1) * 8];
        acc0 = __builtin_amdgcn_mfma_f32_16x16x32_bf16(a, b0, acc0, 0, 0, 0);
        acc1 = __builtin_amdgcn_mfma_f32_16x16x32_bf16(a, b1v, acc1, 0, 0, 0);
      }
#pragma unroll
      for (int r = 0; r < 4; ++r) {
        int row = rsub * 16 + l4 * 4 + r;
        stx(ldsX, 512, row, col0, f2bf(fmaxf(acc0[r] + bias0, 0.f)));
        stx(ldsX, 512, row, col1, f2bf(fmaxf(acc1[r] + bias1, 0.f)));
      }
    }
  }
  __syncthreads();
  // phase 1: y1 = relu(xcat @ Wm1 + bm1), K=256
  {
    int col0 = wave * 16 + l15, col1 = (wave + 4) * 16 + l15;
    float bias0 = bm1[col0], bias1 = bm1[col1];
    for (int rsub = 0; rsub < 4; ++rsub) {
      int row = rsub * 16 + l15;
      f32x4 acc0 = {0.f, 0.f, 0.f, 0.f};
      f32x4 acc1 = {0.f, 0.f, 0.f, 0.f};
#pragma unroll
      for (int kt = 0; kt < 8; ++kt) {
        int kc = kt * 4 + l4;
        bf16x8 a = ldx8(ldsX, 512, row, kc);
        bf16x8 b0 = *(const bf16x8*)&Wm1f[((size_t)kc * 128 + col0) * 8];
        bf16x8 b1v = *(const bf16x8*)&Wm1f[((size_t)kc * 128 + col1) * 8];
        acc0 = __builtin_amdgcn_mfma_f32_16x16x32_bf16(a, b0, acc0, 0, 0, 0);
        acc1 = __builtin_amdgcn_mfma_f32_16x16x32_bf16(a, b1v, acc1, 0, 0, 0);
      }
#pragma unroll
      for (int r = 0; r < 4; ++r) {
        int row2 = rsub * 16 + l4 * 4 + r;
        stx(ldsY, 256, row2, col0, f2bf(fmaxf(acc0[r] + bias0, 0.f)));
        stx(ldsY, 256, row2, col1, f2bf(fmaxf(acc1[r] + bias1, 0.f)));
      }
    }
  }
  __syncthreads();
  // phase 2: y2 = relu(y1 @ Wm2 + bm2) -> ldsX (256B rows)
  {
    int col0 = wave * 16 + l15, col1 = (wave + 4) * 16 + l15;
    float bias0 = bm2[col0], bias1 = bm2[col1];
    for (int rsub = 0; rsub < 4; ++rsub) {
      int row = rsub * 16 + l15;
      f32x4 acc0 = {0.f, 0.f, 0.f, 0.f};
      f32x4 acc1 = {0.f, 0.f, 0.f, 0.f};
#pragma unroll
      for (int kt = 0; kt < 4; ++kt) {
        int kc = kt * 4 + l4;
        bf16x8 a = ldx8(ldsY, 256, row, kc);
        bf16x8 b0 = *(const bf16x8*)&Wm2f[((size_t)kc * 128 + col0) * 8];
        bf16x8 b1v = *(const bf16x8*)&Wm2f[((size_t)kc * 128 + col1) * 8];
        acc0 = __builtin_amdgcn_mfma_f32_16x16x32_bf16(a, b0, acc0, 0, 0, 0);
        acc1 = __builtin_amdgcn_mfma_f32_16x16x32_bf16(a, b1v, acc1, 0, 0, 0);
      }
#pragma unroll
      for (int r = 0; r < 4; ++r) {
        int row2 = rsub * 16 + l4 * 4 + r;
        stx(ldsX, 256, row2, col0, f2bf(fmaxf(acc0[r] + bias0, 0.f)));
        stx(ldsX, 256, row2, col1, f2bf(fmaxf(acc1[r] + bias1, 0.f)));
      }
    }
  }
  __syncthreads();
  // phase 3: out = y2 @ Wm3, fp32 global
  {
    int col0 = wave * 16 + l15, col1 = (wave + 4) * 16 + l15;
    for (int rsub = 0; rsub < 4; ++rsub) {
      int row = rsub * 16 + l15;
      f32x4 acc0 = {0.f, 0.f, 0.f, 0.f};
      f32x4 acc1 = {0.f, 0.f, 0.f, 0.f};
#pragma unroll
      for (int kt = 0; kt < 4; ++kt) {
        int kc = kt * 4 + l4;
        bf16x8 a = ldx8(ldsX, 256, row, kc);
        bf16x8 b0 = *(const bf16x8*)&Wm3f[((size_t)kc * 128 + col0) * 8];
        bf16x8 b1v = *(const bf16x8*)&Wm3f[((size_t)kc * 128 + col1) * 8];
        acc0 = __builtin_amdgcn_mfma_f32_16x16x32_bf16(a, b0, acc0, 0, 0, 0);
        acc1 = __builtin_amdgcn_mfma_f32_16x16x32_bf16(a, b1v, acc1, 0, 0, 0);
      }
#pragma unroll
      for (int r = 0; r < 4; ++r) {
        int orow = rbase + rsub * 16 + l4 * 4 + r;
        if (orow < NM) {
          out[(size_t)orow * 128 + col0] = acc0[r];
          out[(size_t)orow * 128 + col1] = acc1[r];
        }
      }
    }
  }
}

extern "C" void kernel_launch(void* const* d_in, const int* in_sizes, int n_in,
                              void* d_out, int out_size, void* d_ws, size_t ws_size,
                              hipStream_t stream) {
  const float* feat = (const float*)d_in[0];
  const int* src = (const int*)d_in[1];
  const int* dst = (const int*)d_in[2];
  const int* masked = (const int*)d_in[3];
  const float* W1 = (const float*)d_in[4];
  const float* b1 = (const float*)d_in[5];
  const float* W2 = (const float*)d_in[6];
  const float* b2 = (const float*)d_in[7];
  const float* Wm1 = (const float*)d_in[8];
  const float* bm1 = (const float*)d_in[9];
  const float* Wm2 = (const float*)d_in[10];
  const float* bm2 = (const float*)d_in[11];
  const float* Wm3 = (const float*)d_in[12];
  float* out = (float*)d_out;

  // ---- workspace layout ----
  char* p = (char*)d_ws;
  int* deg = (int*)p;              p += (size_t)NN * 4;
  int* offs = (int*)p;             p += (size_t)NN * 4;
  int* bsum = (int*)p;             p += 128 * 4;
  int* pcnt2 = (int*)p;            p += NSB * 4;
  float* inv = (float*)p;          p += (size_t)NN * 4;
  int* csr = (int*)p;              p += (size_t)NE * 4;
  p = (char*)(((size_t)p + 15) & ~(size_t)15);
  unsigned* parts2 = (unsigned*)p; p += (size_t)NSB * CAP2 * 4;
  unsigned short* featbf = (unsigned short*)p;  p += (size_t)(NN + 1) * 128 * 2;
  unsigned short* agg1 = (unsigned short*)p;    p += (size_t)NN * 128 * 2;
  unsigned short* h1bf = (unsigned short*)p;    p += (size_t)(NN + 1) * 128 * 2;
  unsigned short* agg2bf = (unsigned short*)p;  p += (size_t)NM * 128 * 2;
  unsigned short* W1f = (unsigned short*)p;     p += 16384 * 2;
  unsigned short* W2f = (unsigned short*)p;     p += 16384 * 2;
  unsigned short* Wm1f = (unsigned short*)p;    p += 32768 * 2;
  unsigned short* Wm2f = (unsigned short*)p;    p += 16384 * 2;
  unsigned short* Wm3f = (unsigned short*)p;    p += 16384 * 2;

  (void)hipMemsetAsync(pcnt2, 0, NSB * 4, stream);

  // merged front: partition ∥ feat->bf16 ∥ weight conv ∥ pad zero
  front_k<<<NBP2 + NBTB + NBWC + 1, 256, 0, stream>>>(
      src, dst, parts2, pcnt2, feat, featbf,
      W1, W2, Wm1, Wm2, Wm3, W1f, W2f, Wm1f, Wm2f, Wm3f, h1bf);

  deg2_k<<<NSB, 1024, 0, stream>>>(parts2, pcnt2, deg);
  int nb = (NN + 1023) / 1024;
  scan1_k<<<nb, 1024, 0, stream>>>(deg, offs, bsum, NN);
  scan2_k<<<1, 128, 0, stream>>>(bsum, nb);
  scan3_k<<<(NN + 255) / 256, 256, 0, stream>>>(offs, bsum, deg, inv, NN);
  sort_emit_k<<<NSB, 1024, 0, stream>>>(parts2, pcnt2, offs, deg, csr);

  // GCN layer 1: gather + MFMA
  gather1_k<<<(NN + 7) / 8, 256, 0, stream>>>(featbf, csr, offs, deg, inv, agg1);
  mfma1_k<<<(NN + 63) / 64, 256, 0, stream>>>(agg1, W1f, b1, h1bf);

  // layer-2 aggregation at masked nodes
  gather2_k<<<(NM + 7) / 8, 256, 0, stream>>>(h1bf, masked, csr, offs, deg, inv, agg2bf);

  // fused head
  mlp_fused_k<<<(NM + 63) / 64, 256, 0, stream>>>(agg2bf, featbf, masked,
                                                  W2f, b2, Wm1f, bm1, Wm2f, bm2, Wm3f, out);
}

// Round 12
// 152.460 us; speedup vs baseline: 1.8906x; 1.0403x over previous
//
#include <hip/hip_runtime.h>

#define NN 100000
#define NE 1600000
#define NM 10000
#define NSB 256
#define SUBN 391          // nodes per sub-bucket; 256*391 = 100096 >= NN
#define CAP2 7424         // per-sub-bucket edge capacity
#define PCH 2048
#define NBP2 782          // part2 blocks
#define NBTB 1600         // tobf blocks
#define NBWC 48           // wconv blocks

typedef __attribute__((ext_vector_type(8))) short bf16x8;
typedef __attribute__((ext_vector_type(4))) float f32x4;
typedef __attribute__((ext_vector_type(2))) float f32x2;

__device__ inline float4 ld4(const float* p) { return *(const float4*)p; }
__device__ inline float bf2f(unsigned short u) {
  union { unsigned int i; float f; } c; c.i = ((unsigned int)u) << 16; return c.f;
}
__device__ inline unsigned short f2bf(float f) {
  union { float f; unsigned int i; } c; c.f = f;
  unsigned int u = c.i + 0x7fffu + ((c.i >> 16) & 1u);
  return (unsigned short)(u >> 16);
}
// swizzled LDS helpers (16B-chunk XOR swizzle)
__device__ inline void stx(unsigned char* base, int rowBytes, int row, int col,
                           unsigned short val) {
  int bc = col * 2;
  int c = bc >> 4, cp = c ^ (row & 15);
  *(unsigned short*)&base[row * rowBytes + (cp << 4) + (bc & 15)] = val;
}
__device__ inline bf16x8 ldx8(const unsigned char* base, int rowBytes, int row, int kc) {
  return *(const bf16x8*)&base[row * rowBytes + ((kc ^ (row & 15)) << 4)];
}

__device__ inline void convfrag(const float* W, unsigned short* Wf, int g) {
  int k8 = (g >> 7) << 3, col = g & 127;
  unsigned short tmp[8];
#pragma unroll
  for (int i = 0; i < 8; ++i) tmp[i] = f2bf(W[(k8 + i) * 128 + col]);
  *(uint4*)&Wf[(size_t)g * 8] = *(const uint4*)tmp;
}

// ---------- merged front: part2 partition ∥ feat->bf16 ∥ weight conv ∥ pad zero ----------
__global__ __launch_bounds__(256) void front_k(const int* __restrict__ src,
                                               const int* __restrict__ dst,
                                               unsigned* __restrict__ parts2,
                                               int* __restrict__ pcnt2,
                                               const float* __restrict__ feat,
                                               unsigned short* __restrict__ featbf,
                                               const float* W1, const float* W2,
                                               const float* Wm1, const float* Wm2,
                                               const float* Wm3,
                                               unsigned short* W1f, unsigned short* W2f,
                                               unsigned short* Wm1f, unsigned short* Wm2f,
                                               unsigned short* Wm3f,
                                               unsigned short* __restrict__ h1bf) {
  __shared__ int cntw[4][NSB];
  __shared__ int basew[4][NSB];
  __shared__ int bstart[NSB + 1];
  __shared__ int gbase[NSB];
  __shared__ int wsum[4];
  __shared__ unsigned buf[PCH];
  __shared__ unsigned char bb[PCH];
  const int bid = blockIdx.x;
  const int tid = threadIdx.x;

  if (bid < NBP2) {
    // ---- role: 256-way edge partition ----
    const int wv = tid >> 6;
    const int e0 = bid * PCH;
    for (int i = tid; i < 4 * NSB; i += 256) ((int*)cntw)[i] = 0;
    __syncthreads();
    unsigned pk[8];
    int b_[8], lp_[8];
#pragma unroll
    for (int j = 0; j < 8; ++j) {
      int e = e0 + j * 256 + tid;
      bool ok = e < NE;
      int s = ok ? src[e] : 0;
      int d = ok ? dst[e] : 0;
      int b = d / SUBN;
      int ld = d - b * SUBN;
      pk[j] = ((unsigned)ld << 17) | (unsigned)s;
      b_[j] = ok ? b : -1;
      if (ok) lp_[j] = atomicAdd(&cntw[wv][b], 1);
    }
    __syncthreads();
    int t0 = cntw[0][tid], t1 = cntw[1][tid], t2 = cntw[2][tid], t3 = cntw[3][tid];
    int tot = t0 + t1 + t2 + t3;
    int x = tot;
#pragma unroll
    for (int d = 1; d < 64; d <<= 1) {
      int y = __shfl_up(x, d, 64);
      if ((tid & 63) >= d) x += y;
    }
    if ((tid & 63) == 63) wsum[wv] = x;
    __syncthreads();
    int woff = 0;
#pragma unroll
    for (int w = 0; w < 4; ++w) woff += (w < wv) ? wsum[w] : 0;
    int excl = x + woff - tot;
    bstart[tid] = excl;
    basew[0][tid] = excl;
    basew[1][tid] = excl + t0;
    basew[2][tid] = excl + t0 + t1;
    basew[3][tid] = excl + t0 + t1 + t2;
    gbase[tid] = atomicAdd(&pcnt2[tid], tot);
    if (tid == NSB - 1) bstart[NSB] = excl + tot;
    __syncthreads();
#pragma unroll
    for (int j = 0; j < 8; ++j)
      if (b_[j] >= 0) {
        int pos = basew[wv][b_[j]] + lp_[j];
        buf[pos] = pk[j];
        bb[pos] = (unsigned char)b_[j];
      }
    __syncthreads();
    int total = bstart[NSB];
    for (int i = tid; i < total; i += 256) {
      int b = bb[i];
      int gi = gbase[b] + (i - bstart[b]);
      if (gi < CAP2) parts2[(size_t)b * CAP2 + gi] = buf[i];
    }
  } else if (bid < NBP2 + NBTB) {
    // ---- role: feat fp32 -> bf16 ----
    const int n4 = NN * 128 / 4;
    for (int i = (bid - NBP2) * 256 + tid; i < n4; i += NBTB * 256) {
      float4 v = ld4(feat + (size_t)i * 4);
      unsigned int lo = (unsigned int)f2bf(v.x) | ((unsigned int)f2bf(v.y) << 16);
      unsigned int hi = (unsigned int)f2bf(v.z) | ((unsigned int)f2bf(v.w) << 16);
      ((uint2*)featbf)[i] = make_uint2(lo, hi);
    }
  } else if (bid < NBP2 + NBTB + NBWC) {
    // ---- role: weights -> bf16 fragment layout ----
    int g = (bid - NBP2 - NBTB) * 256 + tid;
    if (g < 2048) convfrag(W1, W1f, g);
    else if (g < 4096) convfrag(W2, W2f, g - 2048);
    else if (g < 8192) convfrag(Wm1, Wm1f, g - 4096);
    else if (g < 10240) convfrag(Wm2, Wm2f, g - 8192);
    else if (g < 12288) convfrag(Wm3, Wm3f, g - 10240);
  } else {
    // ---- role: zero pad rows (featbf[NN], h1bf[NN]) ----
    if (tid < 64) {
      ((unsigned*)(featbf + (size_t)NN * 128))[tid] = 0u;
      ((unsigned*)(h1bf + (size_t)NN * 128))[tid] = 0u;
    }
  }
}

// ---------- fused CSR build: histogram + scans + counting sort + emit, one kernel ----------
__global__ __launch_bounds__(1024) void build_k(const unsigned* __restrict__ parts2,
                                                const int* __restrict__ pcnt2,
                                                int* __restrict__ deg,
                                                int* __restrict__ offs_end,
                                                float* __restrict__ inv,
                                                int* __restrict__ csr) {
  __shared__ int cnt[SUBN];
  __shared__ int scn[512];
  __shared__ int cur[SUBN];
  __shared__ int sbb[NSB];
  __shared__ int sorted[CAP2];
  const int sb = blockIdx.x;
  const int tid = threadIdx.x;
  const int n = min(pcnt2[sb], CAP2);
  const unsigned* p = parts2 + (size_t)sb * CAP2;

  // init
  if (tid < NSB) sbb[tid] = min(pcnt2[tid], CAP2);
  for (int i = tid; i < SUBN; i += 1024) cnt[i] = 0;
  __syncthreads();
  // inclusive scan of sbb (256 entries)
  for (int off = 1; off < NSB; off <<= 1) {
    int t = (tid >= off && tid < NSB) ? sbb[tid - off] : 0;
    __syncthreads();
    if (tid < NSB) sbb[tid] += t;
    __syncthreads();
  }
  // histogram
  for (int i = tid; i < n; i += 1024) atomicAdd(&cnt[p[i] >> 17], 1);
  __syncthreads();
  // inclusive scan of cnt (padded to 512)
  if (tid < 512) scn[tid] = (tid < SUBN) ? cnt[tid] : 0;
  __syncthreads();
  for (int off = 1; off < 512; off <<= 1) {
    int t = (tid >= off && tid < 512) ? scn[tid - off] : 0;
    __syncthreads();
    if (tid < 512) scn[tid] += t;
    __syncthreads();
  }
  const int segbase = (sb == 0) ? 0 : sbb[sb - 1];
  const int base = sb * SUBN;
  // write per-node meta (coalesced) + init cursors (local offsets)
  for (int i = tid; i < SUBN; i += 1024) {
    int c = cnt[i];
    int loff = scn[i] - c;         // local exclusive
    cur[i] = loff;
    int nd = base + i;
    if (nd < NN) {
      deg[nd] = c;
      offs_end[nd] = segbase + loff + c;
      inv[nd] = 1.0f / fmaxf((float)c, 1.0f);
    }
  }
  __syncthreads();
  // counting sort into LDS
  for (int i = tid; i < n; i += 1024) {
    unsigned v = p[i];
    int pos = atomicAdd(&cur[v >> 17], 1);
    sorted[pos] = (int)(v & 0x1FFFFu);
  }
  __syncthreads();
  // coalesced emit
  for (int i = tid; i < n; i += 1024) csr[segbase + i] = sorted[i];
}

// ---------- gather layer 1: all nodes; zero-row pad (index NN); pk-f32 accum ----------
__global__ __launch_bounds__(256) void gather1_k(const unsigned short* __restrict__ featbf,
                                                 const int* __restrict__ csr,
                                                 const int* __restrict__ offs_end,
                                                 const int* __restrict__ degv,
                                                 const float* __restrict__ inv,
                                                 unsigned short* __restrict__ agg1) {
  int v = blockIdx.x * 8 + (threadIdx.x >> 5);
  if (v >= NN) return;
  int lane = threadIdx.x & 31;
  int cnt = degv[v];
  int start = offs_end[v] - cnt;
  const uint2* fb = (const uint2*)featbf;
  f32x2 a01 = {0.f, 0.f}, a23 = {0.f, 0.f};
  int nb8 = (cnt + 7) >> 3;
  for (int it = 0; it < nb8; ++it) {
    int b = start + (it << 3);
    int rem = cnt - (it << 3);
    int sidx[8];
#pragma unroll
    for (int j = 0; j < 8; ++j) {
      int s = csr[b + (j < rem ? j : 0)];
      sidx[j] = (j < rem) ? s : NN;        // NN = zeroed pad row
    }
    uint2 x[8];
#pragma unroll
    for (int j = 0; j < 8; ++j) x[j] = fb[(size_t)sidx[j] * 32 + lane];
#pragma unroll
    for (int j = 0; j < 8; ++j) {
      f32x2 u, w;
      u.x = __uint_as_float(x[j].x << 16);
      u.y = __uint_as_float(x[j].x & 0xFFFF0000u);
      w.x = __uint_as_float(x[j].y << 16);
      w.y = __uint_as_float(x[j].y & 0xFFFF0000u);
      a01 += u;
      a23 += w;
    }
  }
  float iv = inv[v];
  unsigned int lo = (unsigned int)f2bf(a01.x * iv) | ((unsigned int)f2bf(a01.y * iv) << 16);
  unsigned int hi = (unsigned int)f2bf(a23.x * iv) | ((unsigned int)f2bf(a23.y * iv) << 16);
  ((uint2*)agg1)[(size_t)v * 32 + lane] = make_uint2(lo, hi);
}

// ---------- layer-1 MFMA: h1 = relu(agg1 @ W1 + b1), B preloaded in regs ----------
__global__ __launch_bounds__(256) void mfma1_k(const unsigned short* __restrict__ agg1,
                                               const unsigned short* __restrict__ W1f,
                                               const float* __restrict__ b1,
                                               unsigned short* __restrict__ h1bf) {
  const int tid = threadIdx.x;
  const int wave = tid >> 6, lane = tid & 63, l15 = lane & 15, l4 = lane >> 4;
  const int rbase = blockIdx.x * 64;
  int col0 = wave * 16 + l15, col1 = (wave + 4) * 16 + l15;
  bf16x8 Bfr0[4], Bfr1[4];
#pragma unroll
  for (int kt = 0; kt < 4; ++kt) {
    int kc = kt * 4 + l4;
    Bfr0[kt] = *(const bf16x8*)&W1f[((size_t)kc * 128 + col0) * 8];
    Bfr1[kt] = *(const bf16x8*)&W1f[((size_t)kc * 128 + col1) * 8];
  }
  float bias0 = b1[col0], bias1 = b1[col1];
  for (int rsub = 0; rsub < 4; ++rsub) {
    int arow = rbase + rsub * 16 + l15;
    const unsigned short* ap = agg1 + (size_t)min(arow, NN - 1) * 128;
    f32x4 acc0 = {0.f, 0.f, 0.f, 0.f};
    f32x4 acc1 = {0.f, 0.f, 0.f, 0.f};
#pragma unroll
    for (int kt = 0; kt < 4; ++kt) {
      int kc = kt * 4 + l4;
      bf16x8 a = *(const bf16x8*)(ap + kc * 8);
      acc0 = __builtin_amdgcn_mfma_f32_16x16x32_bf16(a, Bfr0[kt], acc0, 0, 0, 0);
      acc1 = __builtin_amdgcn_mfma_f32_16x16x32_bf16(a, Bfr1[kt], acc1, 0, 0, 0);
    }
#pragma unroll
    for (int r = 0; r < 4; ++r) {
      int orow = rbase + rsub * 16 + l4 * 4 + r;
      if (orow < NN) {
        h1bf[(size_t)orow * 128 + col0] = f2bf(fmaxf(acc0[r] + bias0, 0.f));
        h1bf[(size_t)orow * 128 + col1] = f2bf(fmaxf(acc1[r] + bias1, 0.f));
      }
    }
  }
}

// ---------- gather layer 2 at masked nodes (zero-row pad at h1 row NN) ----------
__global__ __launch_bounds__(256) void gather2_k(const unsigned short* __restrict__ h1bf,
                                                 const int* __restrict__ masked,
                                                 const int* __restrict__ csr,
                                                 const int* __restrict__ offs_end,
                                                 const int* __restrict__ degv,
                                                 const float* __restrict__ inv,
                                                 unsigned short* __restrict__ agg2bf) {
  int m = blockIdx.x * 8 + (threadIdx.x >> 5);
  if (m >= NM) return;
  int lane = threadIdx.x & 31;
  int v = masked[m];
  int cnt = degv[v];
  int start = offs_end[v] - cnt;
  const uint2* fb = (const uint2*)h1bf;
  f32x2 a01 = {0.f, 0.f}, a23 = {0.f, 0.f};
  int nb8 = (cnt + 7) >> 3;
  for (int it = 0; it < nb8; ++it) {
    int b = start + (it << 3);
    int rem = cnt - (it << 3);
    int sidx[8];
#pragma unroll
    for (int j = 0; j < 8; ++j) {
      int s = csr[b + (j < rem ? j : 0)];
      sidx[j] = (j < rem) ? s : NN;
    }
    uint2 x[8];
#pragma unroll
    for (int j = 0; j < 8; ++j) x[j] = fb[(size_t)sidx[j] * 32 + lane];
#pragma unroll
    for (int j = 0; j < 8; ++j) {
      f32x2 u, w;
      u.x = __uint_as_float(x[j].x << 16);
      u.y = __uint_as_float(x[j].x & 0xFFFF0000u);
      w.x = __uint_as_float(x[j].y << 16);
      w.y = __uint_as_float(x[j].y & 0xFFFF0000u);
      a01 += u;
      a23 += w;
    }
  }
  float iv = inv[v];
  unsigned int lo = (unsigned int)f2bf(a01.x * iv) | ((unsigned int)f2bf(a01.y * iv) << 16);
  unsigned int hi = (unsigned int)f2bf(a23.x * iv) | ((unsigned int)f2bf(a23.y * iv) << 16);
  ((uint2*)agg2bf)[(size_t)m * 32 + lane] = make_uint2(lo, hi);
}

// ---------- fused head: xcat build + 3-layer MLP, tiles LDS-resident ----------
__global__ __launch_bounds__(256) void mlp_fused_k(const unsigned short* __restrict__ agg2bf,
                                                   const unsigned short* __restrict__ featbf,
                                                   const int* __restrict__ masked,
                                                   const unsigned short* __restrict__ W2f,
                                                   const float* __restrict__ b2,
                                                   const unsigned short* __restrict__ Wm1f,
                                                   const float* __restrict__ bm1,
                                                   const unsigned short* __restrict__ Wm2f,
                                                   const float* __restrict__ bm2,
                                                   const unsigned short* __restrict__ Wm3f,
                                                   float* __restrict__ out) {
  __shared__ unsigned char ldsX[64 * 512];
  __shared__ unsigned char ldsY[64 * 256];
  const int tid = threadIdx.x;
  const int rbase = blockIdx.x * 64;
  const int wave = tid >> 6, lane = tid & 63, l15 = lane & 15, l4 = lane >> 4;
  // phase 0a: feat half of xcat (cols 128..255)
  {
    int grp = tid >> 5, ln = tid & 31;
    uint2 vals[8];
#pragma unroll
    for (int k = 0; k < 8; ++k) {
      int m = rbase + grp * 8 + k;
      vals[k] = make_uint2(0u, 0u);
      if (m < NM) {
        int v = masked[m];
        vals[k] = ((const uint2*)featbf)[(size_t)v * 32 + ln];
      }
    }
#pragma unroll
    for (int k = 0; k < 8; ++k) {
      int row = grp * 8 + k;
      int c = 16 + (ln >> 1);
      *(uint2*)&ldsX[row * 512 + ((c ^ (row & 15)) << 4) + (ln & 1) * 8] = vals[k];
    }
  }
  // phase 0b: left half = relu(agg2 @ W2 + b2)
  {
    int col0 = wave * 16 + l15, col1 = (wave + 4) * 16 + l15;
    float bias0 = b2[col0], bias1 = b2[col1];
    for (int rsub = 0; rsub < 4; ++rsub) {
      int arow = rbase + rsub * 16 + l15;
      const unsigned short* ap = agg2bf + (size_t)min(arow, NM - 1) * 128;
      f32x4 acc0 = {0.f, 0.f, 0.f, 0.f};
      f32x4 acc1 = {0.f, 0.f, 0.f, 0.f};
#pragma unroll
      for (int kt = 0; kt < 4; ++kt) {
        int kc = kt * 4 + l4;
        bf16x8 a = *(const bf16x8*)(ap + kc * 8);
        bf16x8 b0 = *(const bf16x8*)&W2f[((size_t)kc * 128 + col0) * 8];
        bf16x8 b1v = *(const bf16x8*)&W2f[((size_t)kc * 128 + col1) * 8];
        acc0 = __builtin_amdgcn_mfma_f32_16x16x32_bf16(a, b0, acc0, 0, 0, 0);
        acc1 = __builtin_amdgcn_mfma_f32_16x16x32_bf16(a, b1v, acc1, 0, 0, 0);
      }
#pragma unroll
      for (int r = 0; r < 4; ++r) {
        int row = rsub * 16 + l4 * 4 + r;
        stx(ldsX, 512, row, col0, f2bf(fmaxf(acc0[r] + bias0, 0.f)));
        stx(ldsX, 512, row, col1, f2bf(fmaxf(acc1[r] + bias1, 0.f)));
      }
    }
  }
  __syncthreads();
  // phase 1: y1 = relu(xcat @ Wm1 + bm1), K=256
  {
    int col0 = wave * 16 + l15, col1 = (wave + 4) * 16 + l15;
    float bias0 = bm1[col0], bias1 = bm1[col1];
    for (int rsub = 0; rsub < 4; ++rsub) {
      int row = rsub * 16 + l15;
      f32x4 acc0 = {0.f, 0.f, 0.f, 0.f};
      f32x4 acc1 = {0.f, 0.f, 0.f, 0.f};
#pragma unroll
      for (int kt = 0; kt < 8; ++kt) {
        int kc = kt * 4 + l4;
        bf16x8 a = ldx8(ldsX, 512, row, kc);
        bf16x8 b0 = *(const bf16x8*)&Wm1f[((size_t)kc * 128 + col0) * 8];
        bf16x8 b1v = *(const bf16x8*)&Wm1f[((size_t)kc * 128 + col1) * 8];
        acc0 = __builtin_amdgcn_mfma_f32_16x16x32_bf16(a, b0, acc0, 0, 0, 0);
        acc1 = __builtin_amdgcn_mfma_f32_16x16x32_bf16(a, b1v, acc1, 0, 0, 0);
      }
#pragma unroll
      for (int r = 0; r < 4; ++r) {
        int row2 = rsub * 16 + l4 * 4 + r;
        stx(ldsY, 256, row2, col0, f2bf(fmaxf(acc0[r] + bias0, 0.f)));
        stx(ldsY, 256, row2, col1, f2bf(fmaxf(acc1[r] + bias1, 0.f)));
      }
    }
  }
  __syncthreads();
  // phase 2: y2 = relu(y1 @ Wm2 + bm2) -> ldsX (256B rows)
  {
    int col0 = wave * 16 + l15, col1 = (wave + 4) * 16 + l15;
    float bias0 = bm2[col0], bias1 = bm2[col1];
    for (int rsub = 0; rsub < 4; ++rsub) {
      int row = rsub * 16 + l15;
      f32x4 acc0 = {0.f, 0.f, 0.f, 0.f};
      f32x4 acc1 = {0.f, 0.f, 0.f, 0.f};
#pragma unroll
      for (int kt = 0; kt < 4; ++kt) {
        int kc = kt * 4 + l4;
        bf16x8 a = ldx8(ldsY, 256, row, kc);
        bf16x8 b0 = *(const bf16x8*)&Wm2f[((size_t)kc * 128 + col0) * 8];
        bf16x8 b1v = *(const bf16x8*)&Wm2f[((size_t)kc * 128 + col1) * 8];
        acc0 = __builtin_amdgcn_mfma_f32_16x16x32_bf16(a, b0, acc0, 0, 0, 0);
        acc1 = __builtin_amdgcn_mfma_f32_16x16x32_bf16(a, b1v, acc1, 0, 0, 0);
      }
#pragma unroll
      for (int r = 0; r < 4; ++r) {
        int row2 = rsub * 16 + l4 * 4 + r;
        stx(ldsX, 256, row2, col0, f2bf(fmaxf(acc0[r] + bias0, 0.f)));
        stx(ldsX, 256, row2, col1, f2bf(fmaxf(acc1[r] + bias1, 0.f)));
      }
    }
  }
  __syncthreads();
  // phase 3: out = y2 @ Wm3, fp32 global
  {
    int col0 = wave * 16 + l15, col1 = (wave + 4) * 16 + l15;
    for (int rsub = 0; rsub < 4; ++rsub) {
      int row = rsub * 16 + l15;
      f32x4 acc0 = {0.f, 0.f, 0.f, 0.f};
      f32x4 acc1 = {0.f, 0.f, 0.f, 0.f};
#pragma unroll
      for (int kt = 0; kt < 4; ++kt) {
        int kc = kt * 4 + l4;
        bf16x8 a = ldx8(ldsX, 256, row, kc);
        bf16x8 b0 = *(const bf16x8*)&Wm3f[((size_t)kc * 128 + col0) * 8];
        bf16x8 b1v = *(const bf16x8*)&Wm3f[((size_t)kc * 128 + col1) * 8];
        acc0 = __builtin_amdgcn_mfma_f32_16x16x32_bf16(a, b0, acc0, 0, 0, 0);
        acc1 = __builtin_amdgcn_mfma_f32_16x16x32_bf16(a, b1v, acc1, 0, 0, 0);
      }
#pragma unroll
      for (int r = 0; r < 4; ++r) {
        int orow = rbase + rsub * 16 + l4 * 4 + r;
        if (orow < NM) {
          out[(size_t)orow * 128 + col0] = acc0[r];
          out[(size_t)orow * 128 + col1] = acc1[r];
        }
      }
    }
  }
}

extern "C" void kernel_launch(void* const* d_in, const int* in_sizes, int n_in,
                              void* d_out, int out_size, void* d_ws, size_t ws_size,
                              hipStream_t stream) {
  const float* feat = (const float*)d_in[0];
  const int* src = (const int*)d_in[1];
  const int* dst = (const int*)d_in[2];
  const int* masked = (const int*)d_in[3];
  const float* W1 = (const float*)d_in[4];
  const float* b1 = (const float*)d_in[5];
  const float* W2 = (const float*)d_in[6];
  const float* b2 = (const float*)d_in[7];
  const float* Wm1 = (const float*)d_in[8];
  const float* bm1 = (const float*)d_in[9];
  const float* Wm2 = (const float*)d_in[10];
  const float* bm2 = (const float*)d_in[11];
  const float* Wm3 = (const float*)d_in[12];
  float* out = (float*)d_out;

  // ---- workspace layout ----
  char* p = (char*)d_ws;
  int* deg = (int*)p;              p += (size_t)NN * 4;
  int* offs = (int*)p;             p += (size_t)NN * 4;
  int* pcnt2 = (int*)p;            p += NSB * 4;
  float* inv = (float*)p;          p += (size_t)NN * 4;
  int* csr = (int*)p;              p += (size_t)NE * 4;
  p = (char*)(((size_t)p + 15) & ~(size_t)15);
  unsigned* parts2 = (unsigned*)p; p += (size_t)NSB * CAP2 * 4;
  unsigned short* featbf = (unsigned short*)p;  p += (size_t)(NN + 1) * 128 * 2;
  unsigned short* agg1 = (unsigned short*)p;    p += (size_t)NN * 128 * 2;
  unsigned short* h1bf = (unsigned short*)p;    p += (size_t)(NN + 1) * 128 * 2;
  unsigned short* agg2bf = (unsigned short*)p;  p += (size_t)NM * 128 * 2;
  unsigned short* W1f = (unsigned short*)p;     p += 16384 * 2;
  unsigned short* W2f = (unsigned short*)p;     p += 16384 * 2;
  unsigned short* Wm1f = (unsigned short*)p;    p += 32768 * 2;
  unsigned short* Wm2f = (unsigned short*)p;    p += 16384 * 2;
  unsigned short* Wm3f = (unsigned short*)p;    p += 16384 * 2;

  (void)hipMemsetAsync(pcnt2, 0, NSB * 4, stream);

  // merged front: partition ∥ feat->bf16 ∥ weight conv ∥ pad zero
  front_k<<<NBP2 + NBTB + NBWC + 1, 256, 0, stream>>>(
      src, dst, parts2, pcnt2, feat, featbf,
      W1, W2, Wm1, Wm2, Wm3, W1f, W2f, Wm1f, Wm2f, Wm3f, h1bf);

  // fused CSR build (histogram + scans + sort + emit)
  build_k<<<NSB, 1024, 0, stream>>>(parts2, pcnt2, deg, offs, inv, csr);

  // GCN layer 1: gather + MFMA
  gather1_k<<<(NN + 7) / 8, 256, 0, stream>>>(featbf, csr, offs, deg, inv, agg1);
  mfma1_k<<<(NN + 63) / 64, 256, 0, stream>>>(agg1, W1f, b1, h1bf);

  // layer-2 aggregation at masked nodes
  gather2_k<<<(NM + 7) / 8, 256, 0, stream>>>(h1bf, masked, csr, offs, deg, inv, agg2bf);

  // fused head
  mlp_fused_k<<<(NM + 63) / 64, 256, 0, stream>>>(agg2bf, featbf, masked,
                                                  W2f, b2, Wm1f, bm1, Wm2f, bm2, Wm3f, out);
}